// Round 1
// baseline (3441.619 us; speedup 1.0000x reference)
//
#include <hip/hip_runtime.h>

typedef __bf16 bf16;
typedef __attribute__((ext_vector_type(8))) __bf16 bf16x8;
typedef __attribute__((ext_vector_type(4))) __bf16 bf16x4;
typedef __attribute__((ext_vector_type(4))) float  f32x4;

// ---------- helpers ----------
__device__ __forceinline__ f32x4 mfma16(bf16x8 a, bf16x8 b, f32x4 c) {
    return __builtin_amdgcn_mfma_f32_16x16x32_bf16(a, b, c, 0, 0, 0);
}

__device__ __forceinline__ void stash8(bf16* dst, float4 a, float4 b) {
    bf16x8 v;
    v[0] = (bf16)a.x; v[1] = (bf16)a.y; v[2] = (bf16)a.z; v[3] = (bf16)a.w;
    v[4] = (bf16)b.x; v[5] = (bf16)b.y; v[6] = (bf16)b.z; v[7] = (bf16)b.w;
    *reinterpret_cast<bf16x8*>(dst) = v;
}

__device__ __forceinline__ float4 scl4(float4 v, float s) {
    return make_float4(v.x * s, v.y * s, v.z * s, v.w * s);
}

// order-preserving float<->uint encode for atomicMax-based segment max
__device__ __forceinline__ unsigned fenc(float f) {
    unsigned u = __float_as_uint(f);
    return (u & 0x80000000u) ? ~u : (u | 0x80000000u);
}
__device__ __forceinline__ float fdec(unsigned u) {
    unsigned b = (u & 0x80000000u) ? (u ^ 0x80000000u) : ~u;
    return __uint_as_float(b);
}

// 2-M-tile (32 rows) x 4-N-tile (64 cols) MFMA matmul; A from LDS (pitch P elems),
// B from global bf16 weights, row-major W[c][k] with leading dim LDK, KS k-steps of 32.
template<int P, int KS, int LDK>
__device__ __forceinline__ void mm2(const bf16* __restrict__ src, int kofs,
                                    const bf16* __restrict__ W,
                                    int c16, int g, f32x4 (&acc)[2][4]) {
#pragma unroll
    for (int m = 0; m < 2; ++m)
#pragma unroll
        for (int n = 0; n < 4; ++n) acc[m][n] = 0.0f;
#pragma unroll
    for (int s = 0; s < KS; ++s) {
        bf16x8 aA = *reinterpret_cast<const bf16x8*>(src + c16 * P + kofs + s * 32 + g * 8);
        bf16x8 aB = *reinterpret_cast<const bf16x8*>(src + (16 + c16) * P + kofs + s * 32 + g * 8);
#pragma unroll
        for (int n = 0; n < 4; ++n) {
            bf16x8 bb = *reinterpret_cast<const bf16x8*>(W + (n * 16 + c16) * LDK + s * 32 + g * 8);
            acc[0][n] = mfma16(aA, bb, acc[0][n]);
            acc[1][n] = mfma16(aB, bb, acc[1][n]);
        }
    }
}

// single-M-tile (16 rows) variant for the node kernel
template<int P, int KS, int LDK>
__device__ __forceinline__ void mm1(const bf16* __restrict__ src, int kofs,
                                    const bf16* __restrict__ W,
                                    int c16, int g, f32x4 (&acc)[4]) {
#pragma unroll
    for (int n = 0; n < 4; ++n) acc[n] = 0.0f;
#pragma unroll
    for (int s = 0; s < KS; ++s) {
        bf16x8 a = *reinterpret_cast<const bf16x8*>(src + c16 * P + kofs + s * 32 + g * 8);
#pragma unroll
        for (int n = 0; n < 4; ++n) {
            bf16x8 bb = *reinterpret_cast<const bf16x8*>(W + (n * 16 + c16) * LDK + s * 32 + g * 8);
            acc[n] = mfma16(a, bb, acc[n]);
        }
    }
}

__device__ __forceinline__ void storeh2(bf16* hbw, const f32x4 (&acc)[2][4],
                                        const float* __restrict__ bias, int c16, int g) {
#pragma unroll
    for (int n = 0; n < 4; ++n) {
        float bb = bias[n * 16 + c16];
#pragma unroll
        for (int m = 0; m < 2; ++m)
#pragma unroll
            for (int r = 0; r < 4; ++r)
                hbw[(m * 16 + g * 4 + r) * 72 + n * 16 + c16] = (bf16)fmaxf(acc[m][n][r] + bb, 0.0f);
    }
}

__device__ __forceinline__ void storeh1(bf16* hbw, const f32x4 (&acc)[4],
                                        const float* __restrict__ bias, int c16, int g) {
#pragma unroll
    for (int n = 0; n < 4; ++n) {
        float bb = bias[n * 16 + c16];
#pragma unroll
        for (int r = 0; r < 4; ++r)
            hbw[(g * 4 + r) * 72 + n * 16 + c16] = (bf16)fmaxf(acc[n][r] + bb, 0.0f);
    }
}

// ---------- prep: f32 -> bf16 weight conversion ----------
struct PrepArgs {
    const float* src[10];
    bf16* dst[10];
    int ofs[11];
};

__global__ void prep_kernel(PrepArgs a, int total4) {
    int t = blockIdx.x * 256 + threadIdx.x;
    if (t >= total4) return;
    int base = t * 4;
    int k = 0;
    while (k < 9 && base >= a.ofs[k + 1]) ++k;
    int i = base - a.ofs[k];
    float4 v = *reinterpret_cast<const float4*>(a.src[k] + i);
    bf16x4 o;
    o[0] = (bf16)v.x; o[1] = (bf16)v.y; o[2] = (bf16)v.z; o[3] = (bf16)v.w;
    *reinterpret_cast<bf16x4*>(a.dst[k] + i) = o;
}

// ---------- E1: edge MLP + QKV + scores + segment-max ----------
// 4 waves/block, 32 edges/wave, 128 edges/block. No cross-wave sharing.
__global__ __launch_bounds__(256, 2) void e1_kernel(
    const float* __restrict__ x, const int* __restrict__ ei, const float* __restrict__ ea,
    const bf16* __restrict__ W0, const bf16* __restrict__ W1, const bf16* __restrict__ W2,
    const bf16* __restrict__ Wq, const bf16* __restrict__ Wk, const bf16* __restrict__ Wv,
    const float* __restrict__ b0, const float* __restrict__ b1, const float* __restrict__ b2,
    const float* __restrict__ egm, const float* __restrict__ ebe,
    float* __restrict__ scoresOut, unsigned int* __restrict__ smax,
    bf16* __restrict__ Vout, float* __restrict__ eout, int E)
{
    __shared__ bf16 cat[4][32][200];  // [xd|xs|ea] per edge row, pitch 200 (bank-spread)
    __shared__ bf16 hbl[4][32][72];   // hidden-layer buffer, pitch 72
    const int w = threadIdx.x >> 6;
    const int lane = threadIdx.x & 63;
    const int ebase = blockIdx.x * 128 + w * 32;
    bf16* catw = &cat[w][0][0];
    bf16* hbw  = &hbl[w][0][0];

    // ---- stage 32 edges of concat(x_dst, x_src, edge_attr) as bf16
    {
        const int r = lane >> 1, q = lane & 1;  // 2 lanes/row, 32 cols each
        const int e = ebase + r;
        const int dn = ei[E + e];  // dst
        const int sn = ei[e];      // src
        const float4* xd = reinterpret_cast<const float4*>(x) + (size_t)dn * 16 + q * 8;
        const float4* xs = reinterpret_cast<const float4*>(x) + (size_t)sn * 16 + q * 8;
        const float4* ep = reinterpret_cast<const float4*>(ea) + (size_t)e * 16 + q * 8;
        bf16* row = catw + r * 200;
#pragma unroll
        for (int j = 0; j < 4; ++j) {
            stash8(row + q * 32 + j * 8,       xd[2 * j], xd[2 * j + 1]);
            stash8(row + 64 + q * 32 + j * 8,  xs[2 * j], xs[2 * j + 1]);
            stash8(row + 128 + q * 32 + j * 8, ep[2 * j], ep[2 * j + 1]);
        }
    }
    const int g = lane >> 4, c16 = lane & 15;
    f32x4 acc[2][4], acc2[2][4];

    // ---- MLP: L0 (K=192) -> relu -> L1 (K=64) -> relu -> L2 (K=64) + b2
    mm2<200, 6, 192>(catw, 0, W0, c16, g, acc);
    storeh2(hbw, acc, b0, c16, g);
    mm2<72, 2, 64>(hbw, 0, W1, c16, g, acc);
    storeh2(hbw, acc, b1, c16, g);
    mm2<72, 2, 64>(hbw, 0, W2, c16, g, acc2);
#pragma unroll
    for (int n = 0; n < 4; ++n) {
        float bb = b2[n * 16 + c16];
#pragma unroll
        for (int m = 0; m < 2; ++m)
#pragma unroll
            for (int r = 0; r < 4; ++r) acc2[m][n][r] += bb;
    }

    // ---- Q (x_dst), K (x_src) + per-head scores + segment max (atomicMax on encoded uint)
    {
        f32x4 aq[2][4], ak[2][4];
        mm2<200, 2, 64>(catw, 0,  Wq, c16, g, aq);
        mm2<200, 2, 64>(catw, 64, Wk, c16, g, ak);
#pragma unroll
        for (int n = 0; n < 4; ++n) {   // head n == N-tile n (DK=16)
#pragma unroll
            for (int m = 0; m < 2; ++m) {
                float pr[4];
#pragma unroll
                for (int r = 0; r < 4; ++r) pr[r] = aq[m][n][r] * ak[m][n][r];
#pragma unroll
                for (int ms = 1; ms < 16; ms <<= 1)
#pragma unroll
                    for (int r = 0; r < 4; ++r) pr[r] += __shfl_xor(pr[r], ms);
                if (c16 == n) {
#pragma unroll
                    for (int r = 0; r < 4; ++r) {
                        int e2 = ebase + m * 16 + g * 4 + r;
                        float sc = pr[r] * 0.25f;  // / sqrt(16)
                        scoresOut[(size_t)e2 * 4 + n] = sc;
                        atomicMax(&smax[(size_t)ei[E + e2] * 4 + n], fenc(sc));
                    }
                }
            }
        }
    }

    // ---- LayerNorm over 64 channels per edge row (wave-local shuffles)
    float mu[2][4], rs[2][4];
#pragma unroll
    for (int m = 0; m < 2; ++m)
#pragma unroll
        for (int r = 0; r < 4; ++r) {
            float s1 = acc2[m][0][r] + acc2[m][1][r] + acc2[m][2][r] + acc2[m][3][r];
            for (int ms = 1; ms < 16; ms <<= 1) s1 += __shfl_xor(s1, ms);
            float mm = s1 * (1.0f / 64.0f);
            float d0 = acc2[m][0][r] - mm, d1 = acc2[m][1][r] - mm;
            float d2 = acc2[m][2][r] - mm, d3 = acc2[m][3][r] - mm;
            float sq = d0 * d0 + d1 * d1 + d2 * d2 + d3 * d3;
            for (int ms = 1; ms < 16; ms <<= 1) sq += __shfl_xor(sq, ms);
            mu[m][r] = mm;
            rs[m][r] = rsqrtf(sq * (1.0f / 64.0f) + 1e-5f);
        }

    // ---- e_new -> cat[0..63] (for V matmul); e_out = edge_attr + e_new (f32)
#pragma unroll
    for (int n = 0; n < 4; ++n) {
        float gg = egm[n * 16 + c16], bb = ebe[n * 16 + c16];
#pragma unroll
        for (int m = 0; m < 2; ++m)
#pragma unroll
            for (int r = 0; r < 4; ++r) {
                int rowi = m * 16 + g * 4 + r;
                float v = (acc2[m][n][r] - mu[m][r]) * rs[m][r] * gg + bb;
                catw[rowi * 200 + n * 16 + c16] = (bf16)v;
                float eav = (float)catw[rowi * 200 + 128 + n * 16 + c16];
                eout[(size_t)(ebase + rowi) * 64 + n * 16 + c16] = eav + v;
            }
    }

    // ---- V = e_new @ wv.T ; stage to LDS, coalesced bf16 store
    mm2<200, 2, 64>(catw, 0, Wv, c16, g, acc);
#pragma unroll
    for (int n = 0; n < 4; ++n)
#pragma unroll
        for (int m = 0; m < 2; ++m)
#pragma unroll
            for (int r = 0; r < 4; ++r)
                hbw[(m * 16 + g * 4 + r) * 72 + n * 16 + c16] = (bf16)acc[m][n][r];
    {
        const int rr = lane >> 1, half = lane & 1;
        const bf16* sp = hbw + rr * 72 + half * 32;
        bf16* dp = Vout + (size_t)(ebase + rr) * 64 + half * 32;
        *reinterpret_cast<bf16x8*>(dp)      = *reinterpret_cast<const bf16x8*>(sp);
        *reinterpret_cast<bf16x8*>(dp + 8)  = *reinterpret_cast<const bf16x8*>(sp + 8);
        *reinterpret_cast<bf16x8*>(dp + 16) = *reinterpret_cast<const bf16x8*>(sp + 16);
        *reinterpret_cast<bf16x8*>(dp + 24) = *reinterpret_cast<const bf16x8*>(sp + 24);
    }
}

// ---------- E2: exp + segment sums (numerator + denominator) ----------
__global__ __launch_bounds__(256) void e2_kernel(
    const int* __restrict__ ei, const float* __restrict__ scores,
    const unsigned int* __restrict__ smax, const bf16* __restrict__ V,
    float* __restrict__ sumexp, float* __restrict__ macc, int E)
{
    const int t = blockIdx.x * 256 + threadIdx.x;
    const int e = t >> 2, hh = t & 3;
    const int d = ei[E + e];
    const float m = fdec(smax[(size_t)d * 4 + hh]);
    const float sc = scores[(size_t)e * 4 + hh];
    const float ex = __expf(sc - m);
    atomicAdd(&sumexp[(size_t)d * 4 + hh], ex);
    const bf16x8* vp = reinterpret_cast<const bf16x8*>(V + (size_t)e * 64 + hh * 16);
    bf16x8 v0 = vp[0], v1 = vp[1];
    float* mp = macc + (size_t)d * 64 + hh * 16;
#pragma unroll
    for (int j = 0; j < 8; ++j) atomicAdd(mp + j, ex * (float)v0[j]);
#pragma unroll
    for (int j = 0; j < 8; ++j) atomicAdd(mp + 8 + j, ex * (float)v1[j]);
}

// ---------- N: node MLP ----------
__global__ __launch_bounds__(256, 2) void n_kernel(
    const float* __restrict__ x, const float* __restrict__ macc, const float* __restrict__ sumexp,
    const bf16* __restrict__ Wo, const bf16* __restrict__ W0, const bf16* __restrict__ W1,
    const bf16* __restrict__ W2,
    const float* __restrict__ b0, const float* __restrict__ b1, const float* __restrict__ b2,
    const float* __restrict__ ngm, const float* __restrict__ nbe,
    float* __restrict__ xout, int N)
{
    __shared__ bf16 cat[4][16][136];  // [x | msg@wo.T], pitch 136
    __shared__ bf16 hbl[4][16][72];
    const int w = threadIdx.x >> 6, lane = threadIdx.x & 63;
    const int nbase = blockIdx.x * 64 + w * 16;
    bf16* catw = &cat[w][0][0];
    bf16* hbw  = &hbl[w][0][0];

    {   // stage x (bf16) into cat[0..63]; msg = macc/(sumexp+1e-12) into hbw
        const int r = lane >> 2, q = lane & 3;  // 4 lanes/row, 16 cols each (col range == head q)
        const int nd = min(nbase + r, N - 1);
        const float4* xp = reinterpret_cast<const float4*>(x) + (size_t)nd * 16 + q * 4;
        stash8(catw + r * 136 + q * 16,     xp[0], xp[1]);
        stash8(catw + r * 136 + q * 16 + 8, xp[2], xp[3]);
        const float4* mp = reinterpret_cast<const float4*>(macc) + (size_t)nd * 16 + q * 4;
        const float inv = 1.0f / (sumexp[(size_t)nd * 4 + q] + 1e-12f);
        stash8(hbw + r * 72 + q * 16,     scl4(mp[0], inv), scl4(mp[1], inv));
        stash8(hbw + r * 72 + q * 16 + 8, scl4(mp[2], inv), scl4(mp[3], inv));
    }
    const int g = lane >> 4, c16 = lane & 15;
    f32x4 acc[4];

    // msgO = msg @ wo.T  -> cat[64..127]
    mm1<72, 2, 64>(hbw, 0, Wo, c16, g, acc);
#pragma unroll
    for (int n = 0; n < 4; ++n)
#pragma unroll
        for (int r = 0; r < 4; ++r)
            catw[(g * 4 + r) * 136 + 64 + n * 16 + c16] = (bf16)acc[n][r];

    // node MLP
    mm1<136, 4, 128>(catw, 0, W0, c16, g, acc);
    storeh1(hbw, acc, b0, c16, g);
    mm1<72, 2, 64>(hbw, 0, W1, c16, g, acc);
    storeh1(hbw, acc, b1, c16, g);
    mm1<72, 2, 64>(hbw, 0, W2, c16, g, acc);
#pragma unroll
    for (int n = 0; n < 4; ++n) {
        float bb = b2[n * 16 + c16];
#pragma unroll
        for (int r = 0; r < 4; ++r) acc[n][r] += bb;
    }

    // LayerNorm + residual
    float mu[4], rs[4];
#pragma unroll
    for (int r = 0; r < 4; ++r) {
        float s1 = acc[0][r] + acc[1][r] + acc[2][r] + acc[3][r];
        for (int ms = 1; ms < 16; ms <<= 1) s1 += __shfl_xor(s1, ms);
        float mm = s1 * (1.0f / 64.0f);
        float d0 = acc[0][r] - mm, d1 = acc[1][r] - mm, d2 = acc[2][r] - mm, d3 = acc[3][r] - mm;
        float sq = d0 * d0 + d1 * d1 + d2 * d2 + d3 * d3;
        for (int ms = 1; ms < 16; ms <<= 1) sq += __shfl_xor(sq, ms);
        mu[r] = mm;
        rs[r] = rsqrtf(sq * (1.0f / 64.0f) + 1e-5f);
    }
#pragma unroll
    for (int n = 0; n < 4; ++n) {
        float gg = ngm[n * 16 + c16], bb = nbe[n * 16 + c16];
#pragma unroll
        for (int r = 0; r < 4; ++r) {
            int rowi = g * 4 + r;
            int node = nbase + rowi;
            float v = (acc[n][r] - mu[r]) * rs[r] * gg + bb;
            if (node < N) {
                size_t o = (size_t)node * 64 + n * 16 + c16;
                xout[o] = x[o] + v;
            }
        }
    }
}

// ---------- launcher ----------
extern "C" void kernel_launch(void* const* d_in, const int* in_sizes, int n_in,
                              void* d_out, int out_size, void* d_ws, size_t ws_size,
                              hipStream_t stream)
{
    const float* x   = (const float*)d_in[0];
    const int*   ei  = (const int*)d_in[1];
    const float* ea  = (const float*)d_in[2];
    const float* ew0 = (const float*)d_in[3];
    const float* eb0 = (const float*)d_in[4];
    const float* ew1 = (const float*)d_in[5];
    const float* eb1 = (const float*)d_in[6];
    const float* ew2 = (const float*)d_in[7];
    const float* eb2 = (const float*)d_in[8];
    const float* egm = (const float*)d_in[9];
    const float* ebe = (const float*)d_in[10];
    const float* nw0 = (const float*)d_in[11];
    const float* nb0 = (const float*)d_in[12];
    const float* nw1 = (const float*)d_in[13];
    const float* nb1 = (const float*)d_in[14];
    const float* nw2 = (const float*)d_in[15];
    const float* nb2 = (const float*)d_in[16];
    const float* ngm = (const float*)d_in[17];
    const float* nbe = (const float*)d_in[18];
    const float* wq  = (const float*)d_in[19];
    const float* wk  = (const float*)d_in[20];
    const float* wv  = (const float*)d_in[21];
    const float* wo  = (const float*)d_in[22];

    const int Nn = in_sizes[0] / 64;
    const int Ee = in_sizes[1] / 2;

    char* p = (char*)d_ws;
    auto carve = [&](size_t bytes) {
        char* r = p;
        p += (bytes + 255) & ~(size_t)255;
        return r;
    };
    bf16* W0e = (bf16*)carve(64 * 192 * 2);
    bf16* W1e = (bf16*)carve(64 * 64 * 2);
    bf16* W2e = (bf16*)carve(64 * 64 * 2);
    bf16* Wqb = (bf16*)carve(64 * 64 * 2);
    bf16* Wkb = (bf16*)carve(64 * 64 * 2);
    bf16* Wvb = (bf16*)carve(64 * 64 * 2);
    bf16* Wob = (bf16*)carve(64 * 64 * 2);
    bf16* W0n = (bf16*)carve(64 * 128 * 2);
    bf16* W1n = (bf16*)carve(64 * 64 * 2);
    bf16* W2n = (bf16*)carve(64 * 64 * 2);
    float*    scores = (float*)carve((size_t)Ee * 4 * 4);
    unsigned* smax   = (unsigned*)carve((size_t)Nn * 4 * 4);
    float*    sumexp = (float*)carve((size_t)Nn * 4 * 4);
    float*    macc   = (float*)carve((size_t)Nn * 64 * 4);
    bf16*     V      = (bf16*)carve((size_t)Ee * 64 * 2);

    hipMemsetAsync(smax, 0, (size_t)Nn * 4 * 4, stream);
    hipMemsetAsync(sumexp, 0, (size_t)Nn * 4 * 4, stream);
    hipMemsetAsync(macc, 0, (size_t)Nn * 64 * 4, stream);

    PrepArgs pa;
    const float* srcs[10] = {ew0, ew1, ew2, wq, wk, wv, wo, nw0, nw1, nw2};
    bf16* dsts[10]        = {W0e, W1e, W2e, Wqb, Wkb, Wvb, Wob, W0n, W1n, W2n};
    const int sizes[10]   = {12288, 4096, 4096, 4096, 4096, 4096, 4096, 8192, 4096, 4096};
    int acc_ofs = 0;
    for (int i = 0; i < 10; ++i) {
        pa.src[i] = srcs[i];
        pa.dst[i] = dsts[i];
        pa.ofs[i] = acc_ofs;
        acc_ofs += sizes[i];
    }
    pa.ofs[10] = acc_ofs;
    const int total4 = acc_ofs / 4;
    prep_kernel<<<(total4 + 255) / 256, 256, 0, stream>>>(pa, total4);

    float* xout = (float*)d_out;
    float* eout = (float*)d_out + (size_t)Nn * 64;

    e1_kernel<<<Ee / 128, 256, 0, stream>>>(x, ei, ea, W0e, W1e, W2e, Wqb, Wkb, Wvb,
                                            eb0, eb1, eb2, egm, ebe,
                                            scores, smax, V, eout, Ee);

    e2_kernel<<<(Ee * 4) / 256, 256, 0, stream>>>(ei, scores, smax, V, sumexp, macc, Ee);

    n_kernel<<<(Nn + 63) / 64, 256, 0, stream>>>(x, macc, sumexp, Wob, W0n, W1n, W2n,
                                                 nb0, nb1, nb2, ngm, nbe, xout, Nn);
}

// Round 2
// 549.219 us; speedup vs baseline: 6.2664x; 6.2664x over previous
//
#include <hip/hip_runtime.h>

typedef __bf16 bf16;
typedef __attribute__((ext_vector_type(8))) __bf16 bf16x8;
typedef __attribute__((ext_vector_type(4))) __bf16 bf16x4;
typedef __attribute__((ext_vector_type(4))) float  f32x4;

// ---------- helpers ----------
__device__ __forceinline__ f32x4 mfma16(bf16x8 a, bf16x8 b, f32x4 c) {
    return __builtin_amdgcn_mfma_f32_16x16x32_bf16(a, b, c, 0, 0, 0);
}

__device__ __forceinline__ void stash8(bf16* dst, float4 a, float4 b) {
    bf16x8 v;
    v[0] = (bf16)a.x; v[1] = (bf16)a.y; v[2] = (bf16)a.z; v[3] = (bf16)a.w;
    v[4] = (bf16)b.x; v[5] = (bf16)b.y; v[6] = (bf16)b.z; v[7] = (bf16)b.w;
    *reinterpret_cast<bf16x8*>(dst) = v;
}

// 2-M-tile (32 rows) x 4-N-tile (64 cols) MFMA matmul; A from LDS (pitch P elems),
// B from global bf16 weights, row-major W[c][k] with leading dim LDK, KS k-steps of 32.
template<int P, int KS, int LDK>
__device__ __forceinline__ void mm2(const bf16* __restrict__ src, int kofs,
                                    const bf16* __restrict__ W,
                                    int c16, int g, f32x4 (&acc)[2][4]) {
#pragma unroll
    for (int m = 0; m < 2; ++m)
#pragma unroll
        for (int n = 0; n < 4; ++n) acc[m][n] = 0.0f;
#pragma unroll
    for (int s = 0; s < KS; ++s) {
        bf16x8 aA = *reinterpret_cast<const bf16x8*>(src + c16 * P + kofs + s * 32 + g * 8);
        bf16x8 aB = *reinterpret_cast<const bf16x8*>(src + (16 + c16) * P + kofs + s * 32 + g * 8);
#pragma unroll
        for (int n = 0; n < 4; ++n) {
            bf16x8 bb = *reinterpret_cast<const bf16x8*>(W + (n * 16 + c16) * LDK + s * 32 + g * 8);
            acc[0][n] = mfma16(aA, bb, acc[0][n]);
            acc[1][n] = mfma16(aB, bb, acc[1][n]);
        }
    }
}

// single-M-tile (16 rows) variant for the node kernel
template<int P, int KS, int LDK>
__device__ __forceinline__ void mm1(const bf16* __restrict__ src, int kofs,
                                    const bf16* __restrict__ W,
                                    int c16, int g, f32x4 (&acc)[4]) {
#pragma unroll
    for (int n = 0; n < 4; ++n) acc[n] = 0.0f;
#pragma unroll
    for (int s = 0; s < KS; ++s) {
        bf16x8 a = *reinterpret_cast<const bf16x8*>(src + c16 * P + kofs + s * 32 + g * 8);
#pragma unroll
        for (int n = 0; n < 4; ++n) {
            bf16x8 bb = *reinterpret_cast<const bf16x8*>(W + (n * 16 + c16) * LDK + s * 32 + g * 8);
            acc[n] = mfma16(a, bb, acc[n]);
        }
    }
}

__device__ __forceinline__ void storeh2(bf16* hbw, const f32x4 (&acc)[2][4],
                                        const float* __restrict__ bias, int c16, int g) {
#pragma unroll
    for (int n = 0; n < 4; ++n) {
        float bb = bias[n * 16 + c16];
#pragma unroll
        for (int m = 0; m < 2; ++m)
#pragma unroll
            for (int r = 0; r < 4; ++r)
                hbw[(m * 16 + g * 4 + r) * 72 + n * 16 + c16] = (bf16)fmaxf(acc[m][n][r] + bb, 0.0f);
    }
}

__device__ __forceinline__ void storeh1(bf16* hbw, const f32x4 (&acc)[4],
                                        const float* __restrict__ bias, int c16, int g) {
#pragma unroll
    for (int n = 0; n < 4; ++n) {
        float bb = bias[n * 16 + c16];
#pragma unroll
        for (int r = 0; r < 4; ++r)
            hbw[(g * 4 + r) * 72 + n * 16 + c16] = (bf16)fmaxf(acc[n][r] + bb, 0.0f);
    }
}

// ---------- prep: f32 -> bf16 weight conversion ----------
struct PrepArgs {
    const float* src[10];
    bf16* dst[10];
    int ofs[11];
};

__global__ void prep_kernel(PrepArgs a, int total4) {
    int t = blockIdx.x * 256 + threadIdx.x;
    if (t >= total4) return;
    int base = t * 4;
    int k = 0;
    while (k < 9 && base >= a.ofs[k + 1]) ++k;
    int i = base - a.ofs[k];
    float4 v = *reinterpret_cast<const float4*>(a.src[k] + i);
    bf16x4 o;
    o[0] = (bf16)v.x; o[1] = (bf16)v.y; o[2] = (bf16)v.z; o[3] = (bf16)v.w;
    *reinterpret_cast<bf16x4*>(a.dst[k] + i) = o;
}

// ---------- E1: edge MLP + QKV + scores + degree count ----------
// 4 waves/block, 32 edges/wave, 128 edges/block. No cross-wave sharing.
__global__ __launch_bounds__(256, 2) void e1_kernel(
    const float* __restrict__ x, const int* __restrict__ ei, const float* __restrict__ ea,
    const bf16* __restrict__ W0, const bf16* __restrict__ W1, const bf16* __restrict__ W2,
    const bf16* __restrict__ Wq, const bf16* __restrict__ Wk, const bf16* __restrict__ Wv,
    const float* __restrict__ b0, const float* __restrict__ b1, const float* __restrict__ b2,
    const float* __restrict__ egm, const float* __restrict__ ebe,
    float* __restrict__ scoresOut, int* __restrict__ deg,
    bf16* __restrict__ Vout, float* __restrict__ eout, int E)
{
    __shared__ bf16 cat[4][32][200];  // [xd|xs|ea] per edge row, pitch 200 (bank-spread)
    __shared__ bf16 hbl[4][32][72];   // hidden-layer buffer, pitch 72
    const int w = threadIdx.x >> 6;
    const int lane = threadIdx.x & 63;
    const int ebase = blockIdx.x * 128 + w * 32;
    bf16* catw = &cat[w][0][0];
    bf16* hbw  = &hbl[w][0][0];

    // ---- degree count for CSR (one edge per thread over the block's 128 edges)
    if (threadIdx.x < 128) {
        int e = blockIdx.x * 128 + threadIdx.x;
        atomicAdd(&deg[ei[E + e]], 1);
    }

    // ---- stage 32 edges of concat(x_dst, x_src, edge_attr) as bf16
    {
        const int r = lane >> 1, q = lane & 1;  // 2 lanes/row, 32 cols each
        const int e = ebase + r;
        const int dn = ei[E + e];  // dst
        const int sn = ei[e];      // src
        const float4* xd = reinterpret_cast<const float4*>(x) + (size_t)dn * 16 + q * 8;
        const float4* xs = reinterpret_cast<const float4*>(x) + (size_t)sn * 16 + q * 8;
        const float4* ep = reinterpret_cast<const float4*>(ea) + (size_t)e * 16 + q * 8;
        bf16* row = catw + r * 200;
#pragma unroll
        for (int j = 0; j < 4; ++j) {
            stash8(row + q * 32 + j * 8,       xd[2 * j], xd[2 * j + 1]);
            stash8(row + 64 + q * 32 + j * 8,  xs[2 * j], xs[2 * j + 1]);
            stash8(row + 128 + q * 32 + j * 8, ep[2 * j], ep[2 * j + 1]);
        }
    }
    const int g = lane >> 4, c16 = lane & 15;
    f32x4 acc[2][4], acc2[2][4];

    // ---- MLP: L0 (K=192) -> relu -> L1 (K=64) -> relu -> L2 (K=64) + b2
    mm2<200, 6, 192>(catw, 0, W0, c16, g, acc);
    storeh2(hbw, acc, b0, c16, g);
    mm2<72, 2, 64>(hbw, 0, W1, c16, g, acc);
    storeh2(hbw, acc, b1, c16, g);
    mm2<72, 2, 64>(hbw, 0, W2, c16, g, acc2);
#pragma unroll
    for (int n = 0; n < 4; ++n) {
        float bb = b2[n * 16 + c16];
#pragma unroll
        for (int m = 0; m < 2; ++m)
#pragma unroll
            for (int r = 0; r < 4; ++r) acc2[m][n][r] += bb;
    }

    // ---- Q (x_dst), K (x_src) + per-head scores
    {
        f32x4 aq[2][4], ak[2][4];
        mm2<200, 2, 64>(catw, 0,  Wq, c16, g, aq);
        mm2<200, 2, 64>(catw, 64, Wk, c16, g, ak);
#pragma unroll
        for (int n = 0; n < 4; ++n) {   // head n == N-tile n (DK=16)
#pragma unroll
            for (int m = 0; m < 2; ++m) {
                float pr[4];
#pragma unroll
                for (int r = 0; r < 4; ++r) pr[r] = aq[m][n][r] * ak[m][n][r];
#pragma unroll
                for (int ms = 1; ms < 16; ms <<= 1)
#pragma unroll
                    for (int r = 0; r < 4; ++r) pr[r] += __shfl_xor(pr[r], ms);
                if (c16 == n) {
#pragma unroll
                    for (int r = 0; r < 4; ++r) {
                        int e2 = ebase + m * 16 + g * 4 + r;
                        scoresOut[(size_t)e2 * 4 + n] = pr[r] * 0.25f;  // / sqrt(16)
                    }
                }
            }
        }
    }

    // ---- LayerNorm over 64 channels per edge row (wave-local shuffles)
    float mu[2][4], rs[2][4];
#pragma unroll
    for (int m = 0; m < 2; ++m)
#pragma unroll
        for (int r = 0; r < 4; ++r) {
            float s1 = acc2[m][0][r] + acc2[m][1][r] + acc2[m][2][r] + acc2[m][3][r];
            for (int ms = 1; ms < 16; ms <<= 1) s1 += __shfl_xor(s1, ms);
            float mm = s1 * (1.0f / 64.0f);
            float d0 = acc2[m][0][r] - mm, d1 = acc2[m][1][r] - mm;
            float d2 = acc2[m][2][r] - mm, d3 = acc2[m][3][r] - mm;
            float sq = d0 * d0 + d1 * d1 + d2 * d2 + d3 * d3;
            for (int ms = 1; ms < 16; ms <<= 1) sq += __shfl_xor(sq, ms);
            mu[m][r] = mm;
            rs[m][r] = rsqrtf(sq * (1.0f / 64.0f) + 1e-5f);
        }

    // ---- e_new -> cat[0..63] (for V matmul); e_out = edge_attr + e_new (f32)
#pragma unroll
    for (int n = 0; n < 4; ++n) {
        float gg = egm[n * 16 + c16], bb = ebe[n * 16 + c16];
#pragma unroll
        for (int m = 0; m < 2; ++m)
#pragma unroll
            for (int r = 0; r < 4; ++r) {
                int rowi = m * 16 + g * 4 + r;
                float v = (acc2[m][n][r] - mu[m][r]) * rs[m][r] * gg + bb;
                catw[rowi * 200 + n * 16 + c16] = (bf16)v;
                float eav = (float)catw[rowi * 200 + 128 + n * 16 + c16];
                eout[(size_t)(ebase + rowi) * 64 + n * 16 + c16] = eav + v;
            }
    }

    // ---- V = e_new @ wv.T ; stage to LDS, coalesced bf16 store
    mm2<200, 2, 64>(catw, 0, Wv, c16, g, acc);
#pragma unroll
    for (int n = 0; n < 4; ++n)
#pragma unroll
        for (int m = 0; m < 2; ++m)
#pragma unroll
            for (int r = 0; r < 4; ++r)
                hbw[(m * 16 + g * 4 + r) * 72 + n * 16 + c16] = (bf16)acc[m][n][r];
    {
        const int rr = lane >> 1, half = lane & 1;
        const bf16* sp = hbw + rr * 72 + half * 32;
        bf16* dp = Vout + (size_t)(ebase + rr) * 64 + half * 32;
        *reinterpret_cast<bf16x8*>(dp)      = *reinterpret_cast<const bf16x8*>(sp);
        *reinterpret_cast<bf16x8*>(dp + 8)  = *reinterpret_cast<const bf16x8*>(sp + 8);
        *reinterpret_cast<bf16x8*>(dp + 16) = *reinterpret_cast<const bf16x8*>(sp + 16);
        *reinterpret_cast<bf16x8*>(dp + 24) = *reinterpret_cast<const bf16x8*>(sp + 24);
    }
}

// ---------- CSR scan: block-local exclusive scan + hierarchical block sums ----------
__global__ __launch_bounds__(256) void scan1_kernel(const int* __restrict__ deg, int* __restrict__ ofs,
                                                    int* __restrict__ bsum, int N) {
    __shared__ int ws4[4];
    const int t = threadIdx.x, lane = t & 63, w = t >> 6;
    const int i = blockIdx.x * 256 + t;
    const int v = (i < N) ? deg[i] : 0;
    int inc = v;
#pragma unroll
    for (int o = 1; o < 64; o <<= 1) { int u = __shfl_up(inc, o); if (lane >= o) inc += u; }
    if (lane == 63) ws4[w] = inc;
    __syncthreads();
    int add = 0;
    for (int k = 0; k < w; ++k) add += ws4[k];
    if (i < N) ofs[i] = inc - v + add;
    if (t == 255) bsum[blockIdx.x] = inc + add;  // block total
}

__global__ __launch_bounds__(256) void scan2_kernel(int* __restrict__ bsum, int nb) {
    __shared__ int ws4[4];
    const int t = threadIdx.x, lane = t & 63, w = t >> 6;
    const int v = (t < nb) ? bsum[t] : 0;
    int inc = v;
#pragma unroll
    for (int o = 1; o < 64; o <<= 1) { int u = __shfl_up(inc, o); if (lane >= o) inc += u; }
    if (lane == 63) ws4[w] = inc;
    __syncthreads();
    int add = 0;
    for (int k = 0; k < w; ++k) add += ws4[k];
    if (t < nb) bsum[t] = inc - v + add;
}

__global__ __launch_bounds__(256) void scan3_kernel(int* __restrict__ ofs, const int* __restrict__ bsum, int N) {
    const int i = blockIdx.x * 256 + threadIdx.x;
    if (i < N) ofs[i] += bsum[blockIdx.x];
}

// ---------- CSR fill ----------
__global__ __launch_bounds__(256) void fill_kernel(const int* __restrict__ ei, const int* __restrict__ ofs,
                                                   int* __restrict__ cur, int* __restrict__ eidT, int E) {
    const int e = blockIdx.x * 256 + threadIdx.x;
    if (e >= E) return;
    const int d = ei[E + e];
    const int slot = atomicAdd(&cur[d], 1);
    eidT[ofs[d] + slot] = e;
}

// ---------- gather: per-node online softmax + weighted V sum (one wave per node) ----------
__global__ __launch_bounds__(256) void gather_kernel(
    const int* __restrict__ deg, const int* __restrict__ ofs, const int* __restrict__ eidT,
    const float* __restrict__ scores, const bf16* __restrict__ V,
    bf16* __restrict__ msg, int N)
{
    const int w = threadIdx.x >> 6, lane = threadIdx.x & 63;
    const int n = blockIdx.x * 4 + w;
    if (n >= N) return;
    const int cnt = deg[n];
    const int* lst = eidT + ofs[n];
    const int h = lane >> 4;
    float m = -3.4e38f, s = 0.f, acc = 0.f;

    // preload up to 128 edge ids into registers (one per lane, two banks)
    int eA = (lane < cnt) ? lst[lane] : 0;
    int eB = (64 + lane < cnt) ? lst[64 + lane] : 0;
    const int nr = min(cnt, 128);
    if (nr > 0) {
        int e = __shfl(eA, 0);
        float sc = scores[(size_t)e * 4 + h];
        float v  = (float)V[(size_t)e * 64 + lane];
        for (int i = 1; i <= nr; ++i) {
            float sc2 = 0.f, v2 = 0.f;
            if (i < nr) {  // prefetch next edge's data while updating with current
                int e2 = __shfl((i < 64) ? eA : eB, i & 63);
                sc2 = scores[(size_t)e2 * 4 + h];
                v2  = (float)V[(size_t)e2 * 64 + lane];
            }
            float mn = fmaxf(m, sc);
            float c  = __expf(m - mn);
            float ex = __expf(sc - mn);
            s = s * c + ex;
            acc = acc * c + ex * v;
            m = mn;
            sc = sc2; v = v2;
        }
    }
    for (int i = 128; i < cnt; ++i) {  // overflow path (deg > 128), statistically never hit
        int e = lst[i];
        float sc = scores[(size_t)e * 4 + h];
        float v  = (float)V[(size_t)e * 64 + lane];
        float mn = fmaxf(m, sc);
        float c  = __expf(m - mn);
        float ex = __expf(sc - mn);
        s = s * c + ex;
        acc = acc * c + ex * v;
        m = mn;
    }
    msg[(size_t)n * 64 + lane] = (bf16)(acc / (s + 1e-12f));
}

// ---------- N: node MLP ----------
__global__ __launch_bounds__(256, 2) void n_kernel(
    const float* __restrict__ x, const bf16* __restrict__ msg,
    const bf16* __restrict__ Wo, const bf16* __restrict__ W0, const bf16* __restrict__ W1,
    const bf16* __restrict__ W2,
    const float* __restrict__ b0, const float* __restrict__ b1, const float* __restrict__ b2,
    const float* __restrict__ ngm, const float* __restrict__ nbe,
    float* __restrict__ xout, int N)
{
    __shared__ bf16 cat[4][16][136];  // [x | msg@wo.T], pitch 136
    __shared__ bf16 hbl[4][16][72];
    const int w = threadIdx.x >> 6, lane = threadIdx.x & 63;
    const int nbase = blockIdx.x * 64 + w * 16;
    bf16* catw = &cat[w][0][0];
    bf16* hbw  = &hbl[w][0][0];

    {   // stage x (bf16) into cat[0..63]; msg (bf16) into hbw
        const int r = lane >> 2, q = lane & 3;  // 4 lanes/row, 16 cols each
        const int nd = min(nbase + r, N - 1);
        const float4* xp = reinterpret_cast<const float4*>(x) + (size_t)nd * 16 + q * 4;
        stash8(catw + r * 136 + q * 16,     xp[0], xp[1]);
        stash8(catw + r * 136 + q * 16 + 8, xp[2], xp[3]);
        const bf16* mp = msg + (size_t)nd * 64 + q * 16;
        *reinterpret_cast<bf16x8*>(hbw + r * 72 + q * 16)     = *reinterpret_cast<const bf16x8*>(mp);
        *reinterpret_cast<bf16x8*>(hbw + r * 72 + q * 16 + 8) = *reinterpret_cast<const bf16x8*>(mp + 8);
    }
    const int g = lane >> 4, c16 = lane & 15;
    f32x4 acc[4];

    // msgO = msg @ wo.T  -> cat[64..127]
    mm1<72, 2, 64>(hbw, 0, Wo, c16, g, acc);
#pragma unroll
    for (int n = 0; n < 4; ++n)
#pragma unroll
        for (int r = 0; r < 4; ++r)
            catw[(g * 4 + r) * 136 + 64 + n * 16 + c16] = (bf16)acc[n][r];

    // node MLP
    mm1<136, 4, 128>(catw, 0, W0, c16, g, acc);
    storeh1(hbw, acc, b0, c16, g);
    mm1<72, 2, 64>(hbw, 0, W1, c16, g, acc);
    storeh1(hbw, acc, b1, c16, g);
    mm1<72, 2, 64>(hbw, 0, W2, c16, g, acc);
#pragma unroll
    for (int n = 0; n < 4; ++n) {
        float bb = b2[n * 16 + c16];
#pragma unroll
        for (int r = 0; r < 4; ++r) acc[n][r] += bb;
    }

    // LayerNorm + residual
    float mu[4], rs[4];
#pragma unroll
    for (int r = 0; r < 4; ++r) {
        float s1 = acc[0][r] + acc[1][r] + acc[2][r] + acc[3][r];
        for (int ms = 1; ms < 16; ms <<= 1) s1 += __shfl_xor(s1, ms);
        float mm = s1 * (1.0f / 64.0f);
        float d0 = acc[0][r] - mm, d1 = acc[1][r] - mm, d2 = acc[2][r] - mm, d3 = acc[3][r] - mm;
        float sq = d0 * d0 + d1 * d1 + d2 * d2 + d3 * d3;
        for (int ms = 1; ms < 16; ms <<= 1) sq += __shfl_xor(sq, ms);
        mu[r] = mm;
        rs[r] = rsqrtf(sq * (1.0f / 64.0f) + 1e-5f);
    }
#pragma unroll
    for (int n = 0; n < 4; ++n) {
        float gg = ngm[n * 16 + c16], bb = nbe[n * 16 + c16];
#pragma unroll
        for (int r = 0; r < 4; ++r) {
            int rowi = g * 4 + r;
            int node = nbase + rowi;
            float v = (acc[n][r] - mu[r]) * rs[r] * gg + bb;
            if (node < N) {
                size_t o = (size_t)node * 64 + n * 16 + c16;
                xout[o] = x[o] + v;
            }
        }
    }
}

// ---------- launcher ----------
extern "C" void kernel_launch(void* const* d_in, const int* in_sizes, int n_in,
                              void* d_out, int out_size, void* d_ws, size_t ws_size,
                              hipStream_t stream)
{
    const float* x   = (const float*)d_in[0];
    const int*   ei  = (const int*)d_in[1];
    const float* ea  = (const float*)d_in[2];
    const float* ew0 = (const float*)d_in[3];
    const float* eb0 = (const float*)d_in[4];
    const float* ew1 = (const float*)d_in[5];
    const float* eb1 = (const float*)d_in[6];
    const float* ew2 = (const float*)d_in[7];
    const float* eb2 = (const float*)d_in[8];
    const float* egm = (const float*)d_in[9];
    const float* ebe = (const float*)d_in[10];
    const float* nw0 = (const float*)d_in[11];
    const float* nb0 = (const float*)d_in[12];
    const float* nw1 = (const float*)d_in[13];
    const float* nb1 = (const float*)d_in[14];
    const float* nw2 = (const float*)d_in[15];
    const float* nb2 = (const float*)d_in[16];
    const float* ngm = (const float*)d_in[17];
    const float* nbe = (const float*)d_in[18];
    const float* wq  = (const float*)d_in[19];
    const float* wk  = (const float*)d_in[20];
    const float* wv  = (const float*)d_in[21];
    const float* wo  = (const float*)d_in[22];

    const int Nn = in_sizes[0] / 64;
    const int Ee = in_sizes[1] / 2;

    char* p = (char*)d_ws;
    auto carve = [&](size_t bytes) {
        char* r = p;
        p += (bytes + 255) & ~(size_t)255;
        return r;
    };
    bf16* W0e = (bf16*)carve(64 * 192 * 2);
    bf16* W1e = (bf16*)carve(64 * 64 * 2);
    bf16* W2e = (bf16*)carve(64 * 64 * 2);
    bf16* Wqb = (bf16*)carve(64 * 64 * 2);
    bf16* Wkb = (bf16*)carve(64 * 64 * 2);
    bf16* Wvb = (bf16*)carve(64 * 64 * 2);
    bf16* Wob = (bf16*)carve(64 * 64 * 2);
    bf16* W0n = (bf16*)carve(64 * 128 * 2);
    bf16* W1n = (bf16*)carve(64 * 64 * 2);
    bf16* W2n = (bf16*)carve(64 * 64 * 2);
    float* scores = (float*)carve((size_t)Ee * 4 * 4);
    bf16*  V      = (bf16*)carve((size_t)Ee * 64 * 2);
    bf16*  msg    = (bf16*)carve((size_t)Nn * 64 * 2);
    int*   deg    = (int*)carve((size_t)Nn * 4);
    int*   ofs    = (int*)carve((size_t)Nn * 4);
    int*   cur    = (int*)carve((size_t)Nn * 4);
    int*   eidT   = (int*)carve((size_t)Ee * 4);
    int*   bsum   = (int*)carve(((size_t)Nn / 256 + 2) * 4);

    hipMemsetAsync(deg, 0, (size_t)Nn * 4, stream);
    hipMemsetAsync(cur, 0, (size_t)Nn * 4, stream);

    PrepArgs pa;
    const float* srcs[10] = {ew0, ew1, ew2, wq, wk, wv, wo, nw0, nw1, nw2};
    bf16* dsts[10]        = {W0e, W1e, W2e, Wqb, Wkb, Wvb, Wob, W0n, W1n, W2n};
    const int sizes[10]   = {12288, 4096, 4096, 4096, 4096, 4096, 4096, 8192, 4096, 4096};
    int acc_ofs = 0;
    for (int i = 0; i < 10; ++i) {
        pa.src[i] = srcs[i];
        pa.dst[i] = dsts[i];
        pa.ofs[i] = acc_ofs;
        acc_ofs += sizes[i];
    }
    pa.ofs[10] = acc_ofs;
    const int total4 = acc_ofs / 4;
    prep_kernel<<<(total4 + 255) / 256, 256, 0, stream>>>(pa, total4);

    float* xout = (float*)d_out;
    float* eout = (float*)d_out + (size_t)Nn * 64;

    // edge MLP + scores + V + degree histogram
    e1_kernel<<<Ee / 128, 256, 0, stream>>>(x, ei, ea, W0e, W1e, W2e, Wqb, Wkb, Wvb,
                                            eb0, eb1, eb2, egm, ebe,
                                            scores, deg, V, eout, Ee);

    // CSR offsets (exclusive scan of deg)
    const int nb = (Nn + 255) / 256;
    scan1_kernel<<<nb, 256, 0, stream>>>(deg, ofs, bsum, Nn);
    scan2_kernel<<<1, 256, 0, stream>>>(bsum, nb);
    scan3_kernel<<<nb, 256, 0, stream>>>(ofs, bsum, Nn);
    fill_kernel<<<(Ee + 255) / 256, 256, 0, stream>>>(ei, ofs, cur, eidT, Ee);

    // per-node softmax-weighted gather
    gather_kernel<<<(Nn + 3) / 4, 256, 0, stream>>>(deg, ofs, eidT, scores, V, msg, Nn);

    // node MLP
    n_kernel<<<(Nn + 63) / 64, 256, 0, stream>>>(x, msg, Wob, W0n, W1n, W2n,
                                                 nb0, nb1, nb2, ngm, nbe, xout, Nn);
}

// Round 3
// 535.362 us; speedup vs baseline: 6.4286x; 1.0259x over previous
//
#include <hip/hip_runtime.h>

typedef __bf16 bf16;
typedef __attribute__((ext_vector_type(8))) __bf16 bf16x8;
typedef __attribute__((ext_vector_type(4))) __bf16 bf16x4;
typedef __attribute__((ext_vector_type(4))) float  f32x4;

// ---------- helpers ----------
__device__ __forceinline__ f32x4 mfma16(bf16x8 a, bf16x8 b, f32x4 c) {
    return __builtin_amdgcn_mfma_f32_16x16x32_bf16(a, b, c, 0, 0, 0);
}

__device__ __forceinline__ void stash8(bf16* dst, float4 a, float4 b) {
    bf16x8 v;
    v[0] = (bf16)a.x; v[1] = (bf16)a.y; v[2] = (bf16)a.z; v[3] = (bf16)a.w;
    v[4] = (bf16)b.x; v[5] = (bf16)b.y; v[6] = (bf16)b.z; v[7] = (bf16)b.w;
    *reinterpret_cast<bf16x8*>(dst) = v;
}

// load 8 consecutive f32 -> bf16x8 (for direct A-fragment construction)
__device__ __forceinline__ bf16x8 ldf8(const float* p) {
    float4 a = *reinterpret_cast<const float4*>(p);
    float4 b = *reinterpret_cast<const float4*>(p + 4);
    bf16x8 v;
    v[0] = (bf16)a.x; v[1] = (bf16)a.y; v[2] = (bf16)a.z; v[3] = (bf16)a.w;
    v[4] = (bf16)b.x; v[5] = (bf16)b.y; v[6] = (bf16)b.z; v[7] = (bf16)b.w;
    return v;
}

// 2-M-tile (32 rows) x 4-N-tile (64 cols) MFMA matmul; A from LDS (pitch P elems),
// B from global bf16 weights, row-major W[c][k] with leading dim LDK, KS k-steps of 32.
template<int P, int KS, int LDK>
__device__ __forceinline__ void mm2(const bf16* __restrict__ src, int kofs,
                                    const bf16* __restrict__ W,
                                    int c16, int g, f32x4 (&acc)[2][4]) {
#pragma unroll
    for (int m = 0; m < 2; ++m)
#pragma unroll
        for (int n = 0; n < 4; ++n) acc[m][n] = 0.0f;
#pragma unroll
    for (int s = 0; s < KS; ++s) {
        bf16x8 aA = *reinterpret_cast<const bf16x8*>(src + c16 * P + kofs + s * 32 + g * 8);
        bf16x8 aB = *reinterpret_cast<const bf16x8*>(src + (16 + c16) * P + kofs + s * 32 + g * 8);
#pragma unroll
        for (int n = 0; n < 4; ++n) {
            bf16x8 bb = *reinterpret_cast<const bf16x8*>(W + (n * 16 + c16) * LDK + s * 32 + g * 8);
            acc[0][n] = mfma16(aA, bb, acc[0][n]);
            acc[1][n] = mfma16(aB, bb, acc[1][n]);
        }
    }
}

// single-M-tile (16 rows) variant for the node kernel
template<int P, int KS, int LDK>
__device__ __forceinline__ void mm1(const bf16* __restrict__ src, int kofs,
                                    const bf16* __restrict__ W,
                                    int c16, int g, f32x4 (&acc)[4]) {
#pragma unroll
    for (int n = 0; n < 4; ++n) acc[n] = 0.0f;
#pragma unroll
    for (int s = 0; s < KS; ++s) {
        bf16x8 a = *reinterpret_cast<const bf16x8*>(src + c16 * P + kofs + s * 32 + g * 8);
#pragma unroll
        for (int n = 0; n < 4; ++n) {
            bf16x8 bb = *reinterpret_cast<const bf16x8*>(W + (n * 16 + c16) * LDK + s * 32 + g * 8);
            acc[n] = mfma16(a, bb, acc[n]);
        }
    }
}

__device__ __forceinline__ void storeh2(bf16* hbw, const f32x4 (&acc)[2][4],
                                        const float* __restrict__ bias, int c16, int g) {
#pragma unroll
    for (int n = 0; n < 4; ++n) {
        float bb = bias[n * 16 + c16];
#pragma unroll
        for (int m = 0; m < 2; ++m)
#pragma unroll
            for (int r = 0; r < 4; ++r)
                hbw[(m * 16 + g * 4 + r) * 72 + n * 16 + c16] = (bf16)fmaxf(acc[m][n][r] + bb, 0.0f);
    }
}

__device__ __forceinline__ void storeh1(bf16* hbw, const f32x4 (&acc)[4],
                                        const float* __restrict__ bias, int c16, int g) {
#pragma unroll
    for (int n = 0; n < 4; ++n) {
        float bb = bias[n * 16 + c16];
#pragma unroll
        for (int r = 0; r < 4; ++r)
            hbw[(g * 4 + r) * 72 + n * 16 + c16] = (bf16)fmaxf(acc[n][r] + bb, 0.0f);
    }
}

// ---------- prep: f32 -> bf16 weight conversion ----------
struct PrepArgs {
    const float* src[10];
    bf16* dst[10];
    int ofs[11];
};

__global__ void prep_kernel(PrepArgs a, int total4) {
    int t = blockIdx.x * 256 + threadIdx.x;
    if (t >= total4) return;
    int base = t * 4;
    int k = 0;
    while (k < 9 && base >= a.ofs[k + 1]) ++k;
    int i = base - a.ofs[k];
    float4 v = *reinterpret_cast<const float4*>(a.src[k] + i);
    bf16x4 o;
    o[0] = (bf16)v.x; o[1] = (bf16)v.y; o[2] = (bf16)v.z; o[3] = (bf16)v.w;
    *reinterpret_cast<bf16x4*>(a.dst[k] + i) = o;
}

// ---------- E1: edge MLP + QKV + scores + degree count ----------
// 4 waves/block, 32 edges/wave. x_dst/x_src loaded DIRECTLY as A-fragments
// (no LDS staging); only edge_attr + inter-layer transposes use LDS.
__global__ __launch_bounds__(256, 4) void e1_kernel(
    const float* __restrict__ x, const int* __restrict__ ei, const float* __restrict__ ea,
    const bf16* __restrict__ W0, const bf16* __restrict__ W1, const bf16* __restrict__ W2,
    const bf16* __restrict__ Wq, const bf16* __restrict__ Wk, const bf16* __restrict__ Wv,
    const float* __restrict__ b0, const float* __restrict__ b1, const float* __restrict__ b2,
    const float* __restrict__ egm, const float* __restrict__ ebe,
    float* __restrict__ scoresOut, int* __restrict__ deg,
    bf16* __restrict__ Vout, float* __restrict__ eout, int E)
{
    __shared__ bf16 eas[4][32][72];   // edge_attr rows (bf16), pitch 72
    __shared__ bf16 hbl[4][32][72];   // hidden-layer transpose buffer, pitch 72
    const int w = threadIdx.x >> 6;
    const int lane = threadIdx.x & 63;
    const int ebase = blockIdx.x * 128 + w * 32;
    bf16* eaw = &eas[w][0][0];
    bf16* hbw = &hbl[w][0][0];
    const int g = lane >> 4, c16 = lane & 15;

    // ---- degree count for CSR
    if (threadIdx.x < 128) {
        int e = blockIdx.x * 128 + threadIdx.x;
        atomicAdd(&deg[ei[E + e]], 1);
    }

    // ---- stage edge_attr (coalesced) -> LDS bf16
    {
        const int r = lane >> 1, q = lane & 1;
        const float4* ep = reinterpret_cast<const float4*>(ea) + (size_t)(ebase + r) * 16 + q * 8;
        bf16* row = eaw + r * 72 + q * 32;
#pragma unroll
        for (int j = 0; j < 4; ++j) stash8(row + j * 8, ep[2 * j], ep[2 * j + 1]);
    }

    // ---- direct A-fragment loads of x_dst / x_src (per-lane row gathers)
    const int eA0 = ebase + c16, eA1 = ebase + 16 + c16;
    const int dn0 = ei[E + eA0], dn1 = ei[E + eA1];
    const int sn0 = ei[eA0],     sn1 = ei[eA1];
    const float* xd0 = x + (size_t)dn0 * 64;
    const float* xd1 = x + (size_t)dn1 * 64;
    const float* xs0 = x + (size_t)sn0 * 64;
    const float* xs1 = x + (size_t)sn1 * 64;
    bf16x8 fxd[2][2], fxs[2][2];
#pragma unroll
    for (int s = 0; s < 2; ++s) {
        fxd[0][s] = ldf8(xd0 + s * 32 + g * 8);
        fxd[1][s] = ldf8(xd1 + s * 32 + g * 8);
        fxs[0][s] = ldf8(xs0 + s * 32 + g * 8);
        fxs[1][s] = ldf8(xs1 + s * 32 + g * 8);
    }

    // ---- Q (x_dst), K (x_src) + per-head scores (transient registers)
    {
        f32x4 aq[2][4], ak[2][4];
#pragma unroll
        for (int m = 0; m < 2; ++m)
#pragma unroll
            for (int n = 0; n < 4; ++n) { aq[m][n] = 0.0f; ak[m][n] = 0.0f; }
#pragma unroll
        for (int s = 0; s < 2; ++s)
#pragma unroll
            for (int n = 0; n < 4; ++n) {
                bf16x8 bq = *reinterpret_cast<const bf16x8*>(Wq + (n * 16 + c16) * 64 + s * 32 + g * 8);
                bf16x8 bk = *reinterpret_cast<const bf16x8*>(Wk + (n * 16 + c16) * 64 + s * 32 + g * 8);
                aq[0][n] = mfma16(fxd[0][s], bq, aq[0][n]);
                aq[1][n] = mfma16(fxd[1][s], bq, aq[1][n]);
                ak[0][n] = mfma16(fxs[0][s], bk, ak[0][n]);
                ak[1][n] = mfma16(fxs[1][s], bk, ak[1][n]);
            }
#pragma unroll
        for (int n = 0; n < 4; ++n) {
#pragma unroll
            for (int m = 0; m < 2; ++m) {
                float pr[4];
#pragma unroll
                for (int r = 0; r < 4; ++r) pr[r] = aq[m][n][r] * ak[m][n][r];
#pragma unroll
                for (int ms = 1; ms < 16; ms <<= 1)
#pragma unroll
                    for (int r = 0; r < 4; ++r) pr[r] += __shfl_xor(pr[r], ms);
                if (c16 == n) {
#pragma unroll
                    for (int r = 0; r < 4; ++r) {
                        int e2 = ebase + m * 16 + g * 4 + r;
                        scoresOut[(size_t)e2 * 4 + n] = pr[r] * 0.25f;  // / sqrt(16)
                    }
                }
            }
        }
    }

    // ---- L0: W0 * [xd | xs | ea]  (K = 192 in three 64-chunks)
    f32x4 acc[2][4], acc2[2][4];
#pragma unroll
    for (int m = 0; m < 2; ++m)
#pragma unroll
        for (int n = 0; n < 4; ++n) acc[m][n] = 0.0f;
#pragma unroll
    for (int s = 0; s < 2; ++s)
#pragma unroll
        for (int n = 0; n < 4; ++n) {
            bf16x8 bd = *reinterpret_cast<const bf16x8*>(W0 + (n * 16 + c16) * 192 + s * 32 + g * 8);
            acc[0][n] = mfma16(fxd[0][s], bd, acc[0][n]);
            acc[1][n] = mfma16(fxd[1][s], bd, acc[1][n]);
            bf16x8 bs = *reinterpret_cast<const bf16x8*>(W0 + (n * 16 + c16) * 192 + 64 + s * 32 + g * 8);
            acc[0][n] = mfma16(fxs[0][s], bs, acc[0][n]);
            acc[1][n] = mfma16(fxs[1][s], bs, acc[1][n]);
        }
#pragma unroll
    for (int s = 0; s < 2; ++s) {
        bf16x8 ae0 = *reinterpret_cast<const bf16x8*>(eaw + c16 * 72 + s * 32 + g * 8);
        bf16x8 ae1 = *reinterpret_cast<const bf16x8*>(eaw + (16 + c16) * 72 + s * 32 + g * 8);
#pragma unroll
        for (int n = 0; n < 4; ++n) {
            bf16x8 be = *reinterpret_cast<const bf16x8*>(W0 + (n * 16 + c16) * 192 + 128 + s * 32 + g * 8);
            acc[0][n] = mfma16(ae0, be, acc[0][n]);
            acc[1][n] = mfma16(ae1, be, acc[1][n]);
        }
    }

    // ---- relu -> L1 -> relu -> L2 + b2
    storeh2(hbw, acc, b0, c16, g);
    mm2<72, 2, 64>(hbw, 0, W1, c16, g, acc);
    storeh2(hbw, acc, b1, c16, g);
    mm2<72, 2, 64>(hbw, 0, W2, c16, g, acc2);
#pragma unroll
    for (int n = 0; n < 4; ++n) {
        float bb = b2[n * 16 + c16];
#pragma unroll
        for (int m = 0; m < 2; ++m)
#pragma unroll
            for (int r = 0; r < 4; ++r) acc2[m][n][r] += bb;
    }

    // ---- LayerNorm over 64 channels per edge row (wave-local shuffles)
    float mu[2][4], rs[2][4];
#pragma unroll
    for (int m = 0; m < 2; ++m)
#pragma unroll
        for (int r = 0; r < 4; ++r) {
            float s1 = acc2[m][0][r] + acc2[m][1][r] + acc2[m][2][r] + acc2[m][3][r];
            for (int ms = 1; ms < 16; ms <<= 1) s1 += __shfl_xor(s1, ms);
            float mm = s1 * (1.0f / 64.0f);
            float d0 = acc2[m][0][r] - mm, d1 = acc2[m][1][r] - mm;
            float d2 = acc2[m][2][r] - mm, d3 = acc2[m][3][r] - mm;
            float sq = d0 * d0 + d1 * d1 + d2 * d2 + d3 * d3;
            for (int ms = 1; ms < 16; ms <<= 1) sq += __shfl_xor(sq, ms);
            mu[m][r] = mm;
            rs[m][r] = rsqrtf(sq * (1.0f / 64.0f) + 1e-5f);
        }

    // ---- e_new -> hbl (A-layout for V matmul); e_out = edge_attr + e_new (f32)
#pragma unroll
    for (int n = 0; n < 4; ++n) {
        float gg = egm[n * 16 + c16], bb = ebe[n * 16 + c16];
#pragma unroll
        for (int m = 0; m < 2; ++m)
#pragma unroll
            for (int r = 0; r < 4; ++r) {
                int rowi = m * 16 + g * 4 + r;
                float v = (acc2[m][n][r] - mu[m][r]) * rs[m][r] * gg + bb;
                hbw[rowi * 72 + n * 16 + c16] = (bf16)v;
                float eav = (float)eaw[rowi * 72 + n * 16 + c16];
                eout[(size_t)(ebase + rowi) * 64 + n * 16 + c16] = eav + v;
            }
    }

    // ---- V = e_new @ wv.T ; stage to LDS, coalesced bf16 store
    mm2<72, 2, 64>(hbw, 0, Wv, c16, g, acc);
#pragma unroll
    for (int n = 0; n < 4; ++n)
#pragma unroll
        for (int m = 0; m < 2; ++m)
#pragma unroll
            for (int r = 0; r < 4; ++r)
                eaw[(m * 16 + g * 4 + r) * 72 + n * 16 + c16] = (bf16)acc[m][n][r];
    {
        const int rr = lane >> 1, half = lane & 1;
        const bf16* sp = eaw + rr * 72 + half * 32;
        bf16* dp = Vout + (size_t)(ebase + rr) * 64 + half * 32;
        *reinterpret_cast<bf16x8*>(dp)      = *reinterpret_cast<const bf16x8*>(sp);
        *reinterpret_cast<bf16x8*>(dp + 8)  = *reinterpret_cast<const bf16x8*>(sp + 8);
        *reinterpret_cast<bf16x8*>(dp + 16) = *reinterpret_cast<const bf16x8*>(sp + 16);
        *reinterpret_cast<bf16x8*>(dp + 24) = *reinterpret_cast<const bf16x8*>(sp + 24);
    }
}

// ---------- CSR scan: block-local exclusive scan + hierarchical block sums ----------
__global__ __launch_bounds__(256) void scan1_kernel(const int* __restrict__ deg, int* __restrict__ ofs,
                                                    int* __restrict__ bsum, int N) {
    __shared__ int ws4[4];
    const int t = threadIdx.x, lane = t & 63, w = t >> 6;
    const int i = blockIdx.x * 256 + t;
    const int v = (i < N) ? deg[i] : 0;
    int inc = v;
#pragma unroll
    for (int o = 1; o < 64; o <<= 1) { int u = __shfl_up(inc, o); if (lane >= o) inc += u; }
    if (lane == 63) ws4[w] = inc;
    __syncthreads();
    int add = 0;
    for (int k = 0; k < w; ++k) add += ws4[k];
    if (i < N) ofs[i] = inc - v + add;
    if (t == 255) bsum[blockIdx.x] = inc + add;  // block total
}

__global__ __launch_bounds__(256) void scan2_kernel(int* __restrict__ bsum, int nb) {
    __shared__ int ws4[4];
    const int t = threadIdx.x, lane = t & 63, w = t >> 6;
    const int v = (t < nb) ? bsum[t] : 0;
    int inc = v;
#pragma unroll
    for (int o = 1; o < 64; o <<= 1) { int u = __shfl_up(inc, o); if (lane >= o) inc += u; }
    if (lane == 63) ws4[w] = inc;
    __syncthreads();
    int add = 0;
    for (int k = 0; k < w; ++k) add += ws4[k];
    if (t < nb) bsum[t] = inc - v + add;
}

__global__ __launch_bounds__(256) void scan3_kernel(int* __restrict__ ofs, const int* __restrict__ bsum, int N) {
    const int i = blockIdx.x * 256 + threadIdx.x;
    if (i < N) ofs[i] += bsum[blockIdx.x];
}

// ---------- CSR fill ----------
__global__ __launch_bounds__(256) void fill_kernel(const int* __restrict__ ei, const int* __restrict__ ofs,
                                                   int* __restrict__ cur, int* __restrict__ eidT, int E) {
    const int e = blockIdx.x * 256 + threadIdx.x;
    if (e >= E) return;
    const int d = ei[E + e];
    const int slot = atomicAdd(&cur[d], 1);
    eidT[ofs[d] + slot] = e;
}

// ---------- gather: per-node online softmax + weighted V sum (one wave per node) ----------
__global__ __launch_bounds__(256) void gather_kernel(
    const int* __restrict__ deg, const int* __restrict__ ofs, const int* __restrict__ eidT,
    const float* __restrict__ scores, const bf16* __restrict__ V,
    bf16* __restrict__ msg, int N)
{
    const int w = threadIdx.x >> 6, lane = threadIdx.x & 63;
    const int n = blockIdx.x * 4 + w;
    if (n >= N) return;
    const int cnt = deg[n];
    const int* lst = eidT + ofs[n];
    const int h = lane >> 4;
    float m = -3.4e38f, s = 0.f, acc = 0.f;

    // preload up to 128 edge ids into registers (one per lane, two banks)
    int eA = (lane < cnt) ? lst[lane] : 0;
    int eB = (64 + lane < cnt) ? lst[64 + lane] : 0;
    const int nr = min(cnt, 128);
    if (nr > 0) {
        int e = __shfl(eA, 0);
        float sc = scores[(size_t)e * 4 + h];
        float v  = (float)V[(size_t)e * 64 + lane];
        for (int i = 1; i <= nr; ++i) {
            float sc2 = 0.f, v2 = 0.f;
            if (i < nr) {  // prefetch next edge's data while updating with current
                int e2 = __shfl((i < 64) ? eA : eB, i & 63);
                sc2 = scores[(size_t)e2 * 4 + h];
                v2  = (float)V[(size_t)e2 * 64 + lane];
            }
            float mn = fmaxf(m, sc);
            float c  = __expf(m - mn);
            float ex = __expf(sc - mn);
            s = s * c + ex;
            acc = acc * c + ex * v;
            m = mn;
            sc = sc2; v = v2;
        }
    }
    for (int i = 128; i < cnt; ++i) {  // overflow path (deg > 128), statistically never hit
        int e = lst[i];
        float sc = scores[(size_t)e * 4 + h];
        float v  = (float)V[(size_t)e * 64 + lane];
        float mn = fmaxf(m, sc);
        float c  = __expf(m - mn);
        float ex = __expf(sc - mn);
        s = s * c + ex;
        acc = acc * c + ex * v;
        m = mn;
    }
    msg[(size_t)n * 64 + lane] = (bf16)(acc / (s + 1e-12f));
}

// ---------- N: node MLP ----------
__global__ __launch_bounds__(256, 2) void n_kernel(
    const float* __restrict__ x, const bf16* __restrict__ msg,
    const bf16* __restrict__ Wo, const bf16* __restrict__ W0, const bf16* __restrict__ W1,
    const bf16* __restrict__ W2,
    const float* __restrict__ b0, const float* __restrict__ b1, const float* __restrict__ b2,
    const float* __restrict__ ngm, const float* __restrict__ nbe,
    float* __restrict__ xout, int N)
{
    __shared__ bf16 cat[4][16][136];  // [x | msg@wo.T], pitch 136
    __shared__ bf16 hbl[4][16][72];
    const int w = threadIdx.x >> 6, lane = threadIdx.x & 63;
    const int nbase = blockIdx.x * 64 + w * 16;
    bf16* catw = &cat[w][0][0];
    bf16* hbw  = &hbl[w][0][0];

    {   // stage x (bf16) into cat[0..63]; msg (bf16) into hbw
        const int r = lane >> 2, q = lane & 3;  // 4 lanes/row, 16 cols each
        const int nd = min(nbase + r, N - 1);
        const float4* xp = reinterpret_cast<const float4*>(x) + (size_t)nd * 16 + q * 4;
        stash8(catw + r * 136 + q * 16,     xp[0], xp[1]);
        stash8(catw + r * 136 + q * 16 + 8, xp[2], xp[3]);
        const bf16* mp = msg + (size_t)nd * 64 + q * 16;
        *reinterpret_cast<bf16x8*>(hbw + r * 72 + q * 16)     = *reinterpret_cast<const bf16x8*>(mp);
        *reinterpret_cast<bf16x8*>(hbw + r * 72 + q * 16 + 8) = *reinterpret_cast<const bf16x8*>(mp + 8);
    }
    const int g = lane >> 4, c16 = lane & 15;
    f32x4 acc[4];

    // msgO = msg @ wo.T  -> cat[64..127]
    mm1<72, 2, 64>(hbw, 0, Wo, c16, g, acc);
#pragma unroll
    for (int n = 0; n < 4; ++n)
#pragma unroll
        for (int r = 0; r < 4; ++r)
            catw[(g * 4 + r) * 136 + 64 + n * 16 + c16] = (bf16)acc[n][r];

    // node MLP
    mm1<136, 4, 128>(catw, 0, W0, c16, g, acc);
    storeh1(hbw, acc, b0, c16, g);
    mm1<72, 2, 64>(hbw, 0, W1, c16, g, acc);
    storeh1(hbw, acc, b1, c16, g);
    mm1<72, 2, 64>(hbw, 0, W2, c16, g, acc);
#pragma unroll
    for (int n = 0; n < 4; ++n) {
        float bb = b2[n * 16 + c16];
#pragma unroll
        for (int r = 0; r < 4; ++r) acc[n][r] += bb;
    }

    // LayerNorm + residual
    float mu[4], rs[4];
#pragma unroll
    for (int r = 0; r < 4; ++r) {
        float s1 = acc[0][r] + acc[1][r] + acc[2][r] + acc[3][r];
        for (int ms = 1; ms < 16; ms <<= 1) s1 += __shfl_xor(s1, ms);
        float mm = s1 * (1.0f / 64.0f);
        float d0 = acc[0][r] - mm, d1 = acc[1][r] - mm, d2 = acc[2][r] - mm, d3 = acc[3][r] - mm;
        float sq = d0 * d0 + d1 * d1 + d2 * d2 + d3 * d3;
        for (int ms = 1; ms < 16; ms <<= 1) sq += __shfl_xor(sq, ms);
        mu[r] = mm;
        rs[r] = rsqrtf(sq * (1.0f / 64.0f) + 1e-5f);
    }
#pragma unroll
    for (int n = 0; n < 4; ++n) {
        float gg = ngm[n * 16 + c16], bb = nbe[n * 16 + c16];
#pragma unroll
        for (int r = 0; r < 4; ++r) {
            int rowi = g * 4 + r;
            int node = nbase + rowi;
            float v = (acc[n][r] - mu[r]) * rs[r] * gg + bb;
            if (node < N) {
                size_t o = (size_t)node * 64 + n * 16 + c16;
                xout[o] = x[o] + v;
            }
        }
    }
}

// ---------- launcher ----------
extern "C" void kernel_launch(void* const* d_in, const int* in_sizes, int n_in,
                              void* d_out, int out_size, void* d_ws, size_t ws_size,
                              hipStream_t stream)
{
    const float* x   = (const float*)d_in[0];
    const int*   ei  = (const int*)d_in[1];
    const float* ea  = (const float*)d_in[2];
    const float* ew0 = (const float*)d_in[3];
    const float* eb0 = (const float*)d_in[4];
    const float* ew1 = (const float*)d_in[5];
    const float* eb1 = (const float*)d_in[6];
    const float* ew2 = (const float*)d_in[7];
    const float* eb2 = (const float*)d_in[8];
    const float* egm = (const float*)d_in[9];
    const float* ebe = (const float*)d_in[10];
    const float* nw0 = (const float*)d_in[11];
    const float* nb0 = (const float*)d_in[12];
    const float* nw1 = (const float*)d_in[13];
    const float* nb1 = (const float*)d_in[14];
    const float* nw2 = (const float*)d_in[15];
    const float* nb2 = (const float*)d_in[16];
    const float* ngm = (const float*)d_in[17];
    const float* nbe = (const float*)d_in[18];
    const float* wq  = (const float*)d_in[19];
    const float* wk  = (const float*)d_in[20];
    const float* wv  = (const float*)d_in[21];
    const float* wo  = (const float*)d_in[22];

    const int Nn = in_sizes[0] / 64;
    const int Ee = in_sizes[1] / 2;

    char* p = (char*)d_ws;
    auto carve = [&](size_t bytes) {
        char* r = p;
        p += (bytes + 255) & ~(size_t)255;
        return r;
    };
    bf16* W0e = (bf16*)carve(64 * 192 * 2);
    bf16* W1e = (bf16*)carve(64 * 64 * 2);
    bf16* W2e = (bf16*)carve(64 * 64 * 2);
    bf16* Wqb = (bf16*)carve(64 * 64 * 2);
    bf16* Wkb = (bf16*)carve(64 * 64 * 2);
    bf16* Wvb = (bf16*)carve(64 * 64 * 2);
    bf16* Wob = (bf16*)carve(64 * 64 * 2);
    bf16* W0n = (bf16*)carve(64 * 128 * 2);
    bf16* W1n = (bf16*)carve(64 * 64 * 2);
    bf16* W2n = (bf16*)carve(64 * 64 * 2);
    float* scores = (float*)carve((size_t)Ee * 4 * 4);
    bf16*  V      = (bf16*)carve((size_t)Ee * 64 * 2);
    bf16*  msg    = (bf16*)carve((size_t)Nn * 64 * 2);
    int*   deg    = (int*)carve((size_t)Nn * 4);
    int*   ofs    = (int*)carve((size_t)Nn * 4);
    int*   cur    = (int*)carve((size_t)Nn * 4);
    int*   eidT   = (int*)carve((size_t)Ee * 4);
    int*   bsum   = (int*)carve(((size_t)Nn / 256 + 2) * 4);

    hipMemsetAsync(deg, 0, (size_t)Nn * 4, stream);
    hipMemsetAsync(cur, 0, (size_t)Nn * 4, stream);

    PrepArgs pa;
    const float* srcs[10] = {ew0, ew1, ew2, wq, wk, wv, wo, nw0, nw1, nw2};
    bf16* dsts[10]        = {W0e, W1e, W2e, Wqb, Wkb, Wvb, Wob, W0n, W1n, W2n};
    const int sizes[10]   = {12288, 4096, 4096, 4096, 4096, 4096, 4096, 8192, 4096, 4096};
    int acc_ofs = 0;
    for (int i = 0; i < 10; ++i) {
        pa.src[i] = srcs[i];
        pa.dst[i] = dsts[i];
        pa.ofs[i] = acc_ofs;
        acc_ofs += sizes[i];
    }
    pa.ofs[10] = acc_ofs;
    const int total4 = acc_ofs / 4;
    prep_kernel<<<(total4 + 255) / 256, 256, 0, stream>>>(pa, total4);

    float* xout = (float*)d_out;
    float* eout = (float*)d_out + (size_t)Nn * 64;

    // edge MLP + scores + V + degree histogram
    e1_kernel<<<Ee / 128, 256, 0, stream>>>(x, ei, ea, W0e, W1e, W2e, Wqb, Wkb, Wvb,
                                            eb0, eb1, eb2, egm, ebe,
                                            scores, deg, V, eout, Ee);

    // CSR offsets (exclusive scan of deg)
    const int nb = (Nn + 255) / 256;
    scan1_kernel<<<nb, 256, 0, stream>>>(deg, ofs, bsum, Nn);
    scan2_kernel<<<1, 256, 0, stream>>>(bsum, nb);
    scan3_kernel<<<nb, 256, 0, stream>>>(ofs, bsum, Nn);
    fill_kernel<<<(Ee + 255) / 256, 256, 0, stream>>>(ei, ofs, cur, eidT, Ee);

    // per-node softmax-weighted gather
    gather_kernel<<<(Nn + 3) / 4, 256, 0, stream>>>(deg, ofs, eidT, scores, V, msg, Nn);

    // node MLP
    n_kernel<<<(Nn + 63) / 64, 256, 0, stream>>>(x, msg, Wob, W0n, W1n, W2n,
                                                 nb0, nb1, nb2, ngm, nbe, xout, Nn);
}

// Round 4
// 508.572 us; speedup vs baseline: 6.7672x; 1.0527x over previous
//
#include <hip/hip_runtime.h>

typedef __bf16 bf16;
typedef __attribute__((ext_vector_type(8))) __bf16 bf16x8;
typedef __attribute__((ext_vector_type(4))) __bf16 bf16x4;
typedef __attribute__((ext_vector_type(4))) float  f32x4;

// ---------- helpers ----------
__device__ __forceinline__ f32x4 mfma16(bf16x8 a, bf16x8 b, f32x4 c) {
    return __builtin_amdgcn_mfma_f32_16x16x32_bf16(a, b, c, 0, 0, 0);
}

__device__ __forceinline__ void stash8(bf16* dst, float4 a, float4 b) {
    bf16x8 v;
    v[0] = (bf16)a.x; v[1] = (bf16)a.y; v[2] = (bf16)a.z; v[3] = (bf16)a.w;
    v[4] = (bf16)b.x; v[5] = (bf16)b.y; v[6] = (bf16)b.z; v[7] = (bf16)b.w;
    *reinterpret_cast<bf16x8*>(dst) = v;
}

// load 8 consecutive f32 -> bf16x8 (for direct A-fragment construction)
__device__ __forceinline__ bf16x8 ldf8(const float* p) {
    float4 a = *reinterpret_cast<const float4*>(p);
    float4 b = *reinterpret_cast<const float4*>(p + 4);
    bf16x8 v;
    v[0] = (bf16)a.x; v[1] = (bf16)a.y; v[2] = (bf16)a.z; v[3] = (bf16)a.w;
    v[4] = (bf16)b.x; v[5] = (bf16)b.y; v[6] = (bf16)b.z; v[7] = (bf16)b.w;
    return v;
}

// B-fragment from PRE-SWIZZLED weights: the 64 lanes of a wave read one
// contiguous 1KB block -> 8 cache-line segments instead of 16 scattered rows.
__device__ __forceinline__ bf16x8 wfrag(const bf16* __restrict__ W, int s, int n, int lane) {
    return *reinterpret_cast<const bf16x8*>(W + (((s * 4 + n) * 64 + lane) * 8));
}

// 2-M-tile (32 rows) x 4-N-tile (64 cols) MFMA matmul; A from LDS (pitch P),
// B from swizzled weights, KS k-steps of 32.
template<int P, int KS>
__device__ __forceinline__ void mm2s(const bf16* __restrict__ src, int kofs,
                                     const bf16* __restrict__ W,
                                     int lane, f32x4 (&acc)[2][4]) {
    const int c16 = lane & 15, g = lane >> 4;
#pragma unroll
    for (int m = 0; m < 2; ++m)
#pragma unroll
        for (int n = 0; n < 4; ++n) acc[m][n] = 0.0f;
#pragma unroll
    for (int s = 0; s < KS; ++s) {
        bf16x8 aA = *reinterpret_cast<const bf16x8*>(src + c16 * P + kofs + s * 32 + g * 8);
        bf16x8 aB = *reinterpret_cast<const bf16x8*>(src + (16 + c16) * P + kofs + s * 32 + g * 8);
#pragma unroll
        for (int n = 0; n < 4; ++n) {
            bf16x8 bb = wfrag(W, s, n, lane);
            acc[0][n] = mfma16(aA, bb, acc[0][n]);
            acc[1][n] = mfma16(aB, bb, acc[1][n]);
        }
    }
}

// single-M-tile (16 rows) variant for the node kernel
template<int P, int KS>
__device__ __forceinline__ void mm1s(const bf16* __restrict__ src, int kofs,
                                     const bf16* __restrict__ W,
                                     int lane, f32x4 (&acc)[4]) {
    const int c16 = lane & 15, g = lane >> 4;
#pragma unroll
    for (int n = 0; n < 4; ++n) acc[n] = 0.0f;
#pragma unroll
    for (int s = 0; s < KS; ++s) {
        bf16x8 a = *reinterpret_cast<const bf16x8*>(src + c16 * P + kofs + s * 32 + g * 8);
#pragma unroll
        for (int n = 0; n < 4; ++n) {
            bf16x8 bb = wfrag(W, s, n, lane);
            acc[n] = mfma16(a, bb, acc[n]);
        }
    }
}

__device__ __forceinline__ void storeh2(bf16* hbw, const f32x4 (&acc)[2][4],
                                        const float* __restrict__ bias, int c16, int g) {
#pragma unroll
    for (int n = 0; n < 4; ++n) {
        float bb = bias[n * 16 + c16];
#pragma unroll
        for (int m = 0; m < 2; ++m)
#pragma unroll
            for (int r = 0; r < 4; ++r)
                hbw[(m * 16 + g * 4 + r) * 72 + n * 16 + c16] = (bf16)fmaxf(acc[m][n][r] + bb, 0.0f);
    }
}

__device__ __forceinline__ void storeh1(bf16* hbw, const f32x4 (&acc)[4],
                                        const float* __restrict__ bias, int c16, int g) {
#pragma unroll
    for (int n = 0; n < 4; ++n) {
        float bb = bias[n * 16 + c16];
#pragma unroll
        for (int r = 0; r < 4; ++r)
            hbw[(g * 4 + r) * 72 + n * 16 + c16] = (bf16)fmaxf(acc[n][r] + bb, 0.0f);
    }
}

// ---------- prep: f32 -> bf16 weight conversion + fragment-order swizzle ----------
// Output layout per matrix: frag f = (s*4 + n)*64 + lane, 8 bf16 each, where
// lane = g*16 + c16 and source element = (n*16+c16)*LDK + s*32 + g*8 + j.
struct PrepArgs {
    const float* src[10];
    bf16* dst[10];
    int ofs[11];
    int ldk[10];
};

__global__ void prep_kernel(PrepArgs a, int totalFrag) {
    int t = blockIdx.x * 256 + threadIdx.x;
    if (t >= totalFrag) return;
    int eb = t * 8;
    int k = 0;
    while (k < 9 && eb >= a.ofs[k + 1]) ++k;
    int f = (eb - a.ofs[k]) >> 3;
    int lane = f & 63, n = (f >> 6) & 3, s = f >> 8;
    int c16 = lane & 15, g = lane >> 4;
    const float* sp = a.src[k] + (n * 16 + c16) * a.ldk[k] + s * 32 + g * 8;
    float4 v0 = *reinterpret_cast<const float4*>(sp);
    float4 v1 = *reinterpret_cast<const float4*>(sp + 4);
    stash8(a.dst[k] + (size_t)f * 8, v0, v1);
}

// ---------- E1: edge MLP + QKV + scores + degree count ----------
// 4 waves/block, 32 edges/wave. x_dst/x_src loaded directly as A-fragments;
// ea staged flat-coalesced; weights read from swizzled layout; eout written
// flat-coalesced (full cache lines) via LDS.
__global__ __launch_bounds__(256, 4) void e1_kernel(
    const float* __restrict__ x, const int* __restrict__ ei, const float* __restrict__ ea,
    const bf16* __restrict__ W0, const bf16* __restrict__ W1, const bf16* __restrict__ W2,
    const bf16* __restrict__ Wq, const bf16* __restrict__ Wk, const bf16* __restrict__ Wv,
    const float* __restrict__ b0, const float* __restrict__ b1, const float* __restrict__ b2,
    const float* __restrict__ egm, const float* __restrict__ ebe,
    float* __restrict__ scoresOut, int* __restrict__ deg,
    bf16* __restrict__ Vout, float* __restrict__ eout, int E)
{
    __shared__ bf16 eas[4][32][72];   // edge_attr rows (bf16), pitch 72
    __shared__ bf16 hbl[4][32][72];   // hidden-layer transpose buffer, pitch 72
    const int w = threadIdx.x >> 6;
    const int lane = threadIdx.x & 63;
    const int ebase = blockIdx.x * 128 + w * 32;
    bf16* eaw = &eas[w][0][0];
    bf16* hbw = &hbl[w][0][0];
    const int g = lane >> 4, c16 = lane & 15;

    // ---- degree count for CSR
    if (threadIdx.x < 128) {
        int e = blockIdx.x * 128 + threadIdx.x;
        atomicAdd(&deg[ei[E + e]], 1);
    }

    // ---- stage edge_attr FLAT (coalesced 2KB per instruction pair) -> LDS bf16
    {
        const float4* eaf = reinterpret_cast<const float4*>(ea + (size_t)ebase * 64);
#pragma unroll
        for (int i = 0; i < 4; ++i) {
            float4 va = eaf[i * 128 + lane * 2];
            float4 vb = eaf[i * 128 + lane * 2 + 1];
            int row = i * 8 + (lane >> 3), col = (lane & 7) * 8;
            stash8(eaw + row * 72 + col, va, vb);
        }
    }

    // ---- direct A-fragment loads of x_dst / x_src (per-lane row gathers)
    const int eA0 = ebase + c16, eA1 = ebase + 16 + c16;
    const int dn0 = ei[E + eA0], dn1 = ei[E + eA1];
    const int sn0 = ei[eA0],     sn1 = ei[eA1];
    const float* xd0 = x + (size_t)dn0 * 64;
    const float* xd1 = x + (size_t)dn1 * 64;
    const float* xs0 = x + (size_t)sn0 * 64;
    const float* xs1 = x + (size_t)sn1 * 64;
    bf16x8 fxd[2][2], fxs[2][2];
#pragma unroll
    for (int s = 0; s < 2; ++s) {
        fxd[0][s] = ldf8(xd0 + s * 32 + g * 8);
        fxd[1][s] = ldf8(xd1 + s * 32 + g * 8);
        fxs[0][s] = ldf8(xs0 + s * 32 + g * 8);
        fxs[1][s] = ldf8(xs1 + s * 32 + g * 8);
    }

    // ---- Q (x_dst), K (x_src) + per-head scores (transient registers)
    {
        f32x4 aq[2][4], ak[2][4];
#pragma unroll
        for (int m = 0; m < 2; ++m)
#pragma unroll
            for (int n = 0; n < 4; ++n) { aq[m][n] = 0.0f; ak[m][n] = 0.0f; }
#pragma unroll
        for (int s = 0; s < 2; ++s)
#pragma unroll
            for (int n = 0; n < 4; ++n) {
                bf16x8 bq = wfrag(Wq, s, n, lane);
                bf16x8 bk = wfrag(Wk, s, n, lane);
                aq[0][n] = mfma16(fxd[0][s], bq, aq[0][n]);
                aq[1][n] = mfma16(fxd[1][s], bq, aq[1][n]);
                ak[0][n] = mfma16(fxs[0][s], bk, ak[0][n]);
                ak[1][n] = mfma16(fxs[1][s], bk, ak[1][n]);
            }
#pragma unroll
        for (int n = 0; n < 4; ++n) {
#pragma unroll
            for (int m = 0; m < 2; ++m) {
                float pr[4];
#pragma unroll
                for (int r = 0; r < 4; ++r) pr[r] = aq[m][n][r] * ak[m][n][r];
#pragma unroll
                for (int ms = 1; ms < 16; ms <<= 1)
#pragma unroll
                    for (int r = 0; r < 4; ++r) pr[r] += __shfl_xor(pr[r], ms);
                if (c16 == n) {
#pragma unroll
                    for (int r = 0; r < 4; ++r) {
                        int e2 = ebase + m * 16 + g * 4 + r;
                        scoresOut[(size_t)e2 * 4 + n] = pr[r] * 0.25f;  // / sqrt(16)
                    }
                }
            }
        }
    }

    // ---- L0: W0 * [xd | xs | ea]  (K = 192; swizzled W0 with s6 = 0..5)
    f32x4 acc[2][4], acc2[2][4];
#pragma unroll
    for (int m = 0; m < 2; ++m)
#pragma unroll
        for (int n = 0; n < 4; ++n) acc[m][n] = 0.0f;
#pragma unroll
    for (int s = 0; s < 2; ++s)
#pragma unroll
        for (int n = 0; n < 4; ++n) {
            bf16x8 bd = wfrag(W0, s, n, lane);
            acc[0][n] = mfma16(fxd[0][s], bd, acc[0][n]);
            acc[1][n] = mfma16(fxd[1][s], bd, acc[1][n]);
            bf16x8 bs = wfrag(W0, s + 2, n, lane);
            acc[0][n] = mfma16(fxs[0][s], bs, acc[0][n]);
            acc[1][n] = mfma16(fxs[1][s], bs, acc[1][n]);
        }
#pragma unroll
    for (int s = 0; s < 2; ++s) {
        bf16x8 ae0 = *reinterpret_cast<const bf16x8*>(eaw + c16 * 72 + s * 32 + g * 8);
        bf16x8 ae1 = *reinterpret_cast<const bf16x8*>(eaw + (16 + c16) * 72 + s * 32 + g * 8);
#pragma unroll
        for (int n = 0; n < 4; ++n) {
            bf16x8 be = wfrag(W0, s + 4, n, lane);
            acc[0][n] = mfma16(ae0, be, acc[0][n]);
            acc[1][n] = mfma16(ae1, be, acc[1][n]);
        }
    }

    // ---- relu -> L1 -> relu -> L2 + b2
    storeh2(hbw, acc, b0, c16, g);
    mm2s<72, 2>(hbw, 0, W1, lane, acc);
    storeh2(hbw, acc, b1, c16, g);
    mm2s<72, 2>(hbw, 0, W2, lane, acc2);
#pragma unroll
    for (int n = 0; n < 4; ++n) {
        float bb = b2[n * 16 + c16];
#pragma unroll
        for (int m = 0; m < 2; ++m)
#pragma unroll
            for (int r = 0; r < 4; ++r) acc2[m][n][r] += bb;
    }

    // ---- LayerNorm over 64 channels per edge row (wave-local shuffles)
    float mu[2][4], rs[2][4];
#pragma unroll
    for (int m = 0; m < 2; ++m)
#pragma unroll
        for (int r = 0; r < 4; ++r) {
            float s1 = acc2[m][0][r] + acc2[m][1][r] + acc2[m][2][r] + acc2[m][3][r];
            for (int ms = 1; ms < 16; ms <<= 1) s1 += __shfl_xor(s1, ms);
            float mm = s1 * (1.0f / 64.0f);
            float d0 = acc2[m][0][r] - mm, d1 = acc2[m][1][r] - mm;
            float d2 = acc2[m][2][r] - mm, d3 = acc2[m][3][r] - mm;
            float sq = d0 * d0 + d1 * d1 + d2 * d2 + d3 * d3;
            for (int ms = 1; ms < 16; ms <<= 1) sq += __shfl_xor(sq, ms);
            mu[m][r] = mm;
            rs[m][r] = rsqrtf(sq * (1.0f / 64.0f) + 1e-5f);
        }

    // ---- e_new -> hbl (A-layout, bf16) for V matmul and eout
#pragma unroll
    for (int n = 0; n < 4; ++n) {
        float gg = egm[n * 16 + c16], bb = ebe[n * 16 + c16];
#pragma unroll
        for (int m = 0; m < 2; ++m)
#pragma unroll
            for (int r = 0; r < 4; ++r) {
                int rowi = m * 16 + g * 4 + r;
                float v = (acc2[m][n][r] - mu[m][r]) * rs[m][r] * gg + bb;
                hbw[rowi * 72 + n * 16 + c16] = (bf16)v;
            }
    }

    // ---- eout = edge_attr + e_new, FLAT full-line stores (1KB/instr)
#pragma unroll
    for (int i = 0; i < 4; ++i) {
        int row = i * 8 + (lane >> 3), col = (lane & 7) * 8;
        const bf16* hp = hbw + row * 72 + col;
        const bf16* ap = eaw + row * 72 + col;
        float4 o0, o1;
        o0.x = (float)hp[0] + (float)ap[0];
        o0.y = (float)hp[1] + (float)ap[1];
        o0.z = (float)hp[2] + (float)ap[2];
        o0.w = (float)hp[3] + (float)ap[3];
        o1.x = (float)hp[4] + (float)ap[4];
        o1.y = (float)hp[5] + (float)ap[5];
        o1.z = (float)hp[6] + (float)ap[6];
        o1.w = (float)hp[7] + (float)ap[7];
        float4* op = reinterpret_cast<float4*>(eout + (size_t)(ebase + row) * 64 + col);
        op[0] = o0;
        op[1] = o1;
    }

    // ---- V = e_new @ wv.T ; stage to LDS, coalesced bf16 store
    mm2s<72, 2>(hbw, 0, Wv, lane, acc);
#pragma unroll
    for (int n = 0; n < 4; ++n)
#pragma unroll
        for (int m = 0; m < 2; ++m)
#pragma unroll
            for (int r = 0; r < 4; ++r)
                eaw[(m * 16 + g * 4 + r) * 72 + n * 16 + c16] = (bf16)acc[m][n][r];
    {
        const int rr = lane >> 1, half = lane & 1;
        const bf16* sp = eaw + rr * 72 + half * 32;
        bf16* dp = Vout + (size_t)(ebase + rr) * 64 + half * 32;
        *reinterpret_cast<bf16x8*>(dp)      = *reinterpret_cast<const bf16x8*>(sp);
        *reinterpret_cast<bf16x8*>(dp + 8)  = *reinterpret_cast<const bf16x8*>(sp + 8);
        *reinterpret_cast<bf16x8*>(dp + 16) = *reinterpret_cast<const bf16x8*>(sp + 16);
        *reinterpret_cast<bf16x8*>(dp + 24) = *reinterpret_cast<const bf16x8*>(sp + 24);
    }
}

// ---------- CSR scan: block-local exclusive scan + hierarchical block sums ----------
__global__ __launch_bounds__(256) void scan1_kernel(const int* __restrict__ deg, int* __restrict__ ofs,
                                                    int* __restrict__ bsum, int N) {
    __shared__ int ws4[4];
    const int t = threadIdx.x, lane = t & 63, w = t >> 6;
    const int i = blockIdx.x * 256 + t;
    const int v = (i < N) ? deg[i] : 0;
    int inc = v;
#pragma unroll
    for (int o = 1; o < 64; o <<= 1) { int u = __shfl_up(inc, o); if (lane >= o) inc += u; }
    if (lane == 63) ws4[w] = inc;
    __syncthreads();
    int add = 0;
    for (int k = 0; k < w; ++k) add += ws4[k];
    if (i < N) ofs[i] = inc - v + add;
    if (t == 255) bsum[blockIdx.x] = inc + add;  // block total
}

__global__ __launch_bounds__(256) void scan2_kernel(int* __restrict__ bsum, int nb) {
    __shared__ int ws4[4];
    const int t = threadIdx.x, lane = t & 63, w = t >> 6;
    const int v = (t < nb) ? bsum[t] : 0;
    int inc = v;
#pragma unroll
    for (int o = 1; o < 64; o <<= 1) { int u = __shfl_up(inc, o); if (lane >= o) inc += u; }
    if (lane == 63) ws4[w] = inc;
    __syncthreads();
    int add = 0;
    for (int k = 0; k < w; ++k) add += ws4[k];
    if (t < nb) bsum[t] = inc - v + add;
}

__global__ __launch_bounds__(256) void scan3_kernel(int* __restrict__ ofs, const int* __restrict__ bsum, int N) {
    const int i = blockIdx.x * 256 + threadIdx.x;
    if (i < N) ofs[i] += bsum[blockIdx.x];
}

// ---------- CSR fill ----------
__global__ __launch_bounds__(256) void fill_kernel(const int* __restrict__ ei, const int* __restrict__ ofs,
                                                   int* __restrict__ cur, int* __restrict__ eidT, int E) {
    const int e = blockIdx.x * 256 + threadIdx.x;
    if (e >= E) return;
    const int d = ei[E + e];
    const int slot = atomicAdd(&cur[d], 1);
    eidT[ofs[d] + slot] = e;
}

// ---------- gather: per-node online softmax + weighted V sum (one wave per node) ----------
__global__ __launch_bounds__(256) void gather_kernel(
    const int* __restrict__ deg, const int* __restrict__ ofs, const int* __restrict__ eidT,
    const float* __restrict__ scores, const bf16* __restrict__ V,
    bf16* __restrict__ msg, int N)
{
    const int w = threadIdx.x >> 6, lane = threadIdx.x & 63;
    const int n = blockIdx.x * 4 + w;
    if (n >= N) return;
    const int cnt = deg[n];
    const int* lst = eidT + ofs[n];
    const int h = lane >> 4;
    float m = -3.4e38f, s = 0.f, acc = 0.f;

    // preload up to 128 edge ids into registers (one per lane, two banks)
    int eA = (lane < cnt) ? lst[lane] : 0;
    int eB = (64 + lane < cnt) ? lst[64 + lane] : 0;
    const int nr = min(cnt, 128);
    if (nr > 0) {
        int e = __shfl(eA, 0);
        float sc = scores[(size_t)e * 4 + h];
        float v  = (float)V[(size_t)e * 64 + lane];
        for (int i = 1; i <= nr; ++i) {
            float sc2 = 0.f, v2 = 0.f;
            if (i < nr) {  // prefetch next edge's data while updating with current
                int e2 = __shfl((i < 64) ? eA : eB, i & 63);
                sc2 = scores[(size_t)e2 * 4 + h];
                v2  = (float)V[(size_t)e2 * 64 + lane];
            }
            float mn = fmaxf(m, sc);
            float c  = __expf(m - mn);
            float ex = __expf(sc - mn);
            s = s * c + ex;
            acc = acc * c + ex * v;
            m = mn;
            sc = sc2; v = v2;
        }
    }
    for (int i = 128; i < cnt; ++i) {  // overflow path (deg > 128), statistically never hit
        int e = lst[i];
        float sc = scores[(size_t)e * 4 + h];
        float v  = (float)V[(size_t)e * 64 + lane];
        float mn = fmaxf(m, sc);
        float c  = __expf(m - mn);
        float ex = __expf(sc - mn);
        s = s * c + ex;
        acc = acc * c + ex * v;
        m = mn;
    }
    msg[(size_t)n * 64 + lane] = (bf16)(acc / (s + 1e-12f));
}

// ---------- N: node MLP ----------
__global__ __launch_bounds__(256, 2) void n_kernel(
    const float* __restrict__ x, const bf16* __restrict__ msg,
    const bf16* __restrict__ Wo, const bf16* __restrict__ W0, const bf16* __restrict__ W1,
    const bf16* __restrict__ W2,
    const float* __restrict__ b0, const float* __restrict__ b1, const float* __restrict__ b2,
    const float* __restrict__ ngm, const float* __restrict__ nbe,
    float* __restrict__ xout, int N)
{
    __shared__ bf16 cat[4][16][136];  // [x | msg@wo.T], pitch 136
    __shared__ bf16 hbl[4][16][72];
    const int w = threadIdx.x >> 6, lane = threadIdx.x & 63;
    const int nbase = blockIdx.x * 64 + w * 16;
    bf16* catw = &cat[w][0][0];
    bf16* hbw  = &hbl[w][0][0];

    {   // stage x (bf16) into cat[0..63]; msg (bf16) into hbw
        const int r = lane >> 2, q = lane & 3;  // 4 lanes/row, 16 cols each
        const int nd = min(nbase + r, N - 1);
        const float4* xp = reinterpret_cast<const float4*>(x) + (size_t)nd * 16 + q * 4;
        stash8(catw + r * 136 + q * 16,     xp[0], xp[1]);
        stash8(catw + r * 136 + q * 16 + 8, xp[2], xp[3]);
        const bf16* mp = msg + (size_t)nd * 64 + q * 16;
        *reinterpret_cast<bf16x8*>(hbw + r * 72 + q * 16)     = *reinterpret_cast<const bf16x8*>(mp);
        *reinterpret_cast<bf16x8*>(hbw + r * 72 + q * 16 + 8) = *reinterpret_cast<const bf16x8*>(mp + 8);
    }
    const int g = lane >> 4, c16 = lane & 15;
    f32x4 acc[4];

    // msgO = msg @ wo.T  -> cat[64..127]
    mm1s<72, 2>(hbw, 0, Wo, lane, acc);
#pragma unroll
    for (int n = 0; n < 4; ++n)
#pragma unroll
        for (int r = 0; r < 4; ++r)
            catw[(g * 4 + r) * 136 + 64 + n * 16 + c16] = (bf16)acc[n][r];

    // node MLP
    mm1s<136, 4>(catw, 0, W0, lane, acc);
    storeh1(hbw, acc, b0, c16, g);
    mm1s<72, 2>(hbw, 0, W1, lane, acc);
    storeh1(hbw, acc, b1, c16, g);
    mm1s<72, 2>(hbw, 0, W2, lane, acc);
#pragma unroll
    for (int n = 0; n < 4; ++n) {
        float bb = b2[n * 16 + c16];
#pragma unroll
        for (int r = 0; r < 4; ++r) acc[n][r] += bb;
    }

    // LayerNorm + residual
    float mu[4], rs[4];
#pragma unroll
    for (int r = 0; r < 4; ++r) {
        float s1 = acc[0][r] + acc[1][r] + acc[2][r] + acc[3][r];
        for (int ms = 1; ms < 16; ms <<= 1) s1 += __shfl_xor(s1, ms);
        float mm = s1 * (1.0f / 64.0f);
        float d0 = acc[0][r] - mm, d1 = acc[1][r] - mm, d2 = acc[2][r] - mm, d3 = acc[3][r] - mm;
        float sq = d0 * d0 + d1 * d1 + d2 * d2 + d3 * d3;
        for (int ms = 1; ms < 16; ms <<= 1) sq += __shfl_xor(sq, ms);
        mu[r] = mm;
        rs[r] = rsqrtf(sq * (1.0f / 64.0f) + 1e-5f);
    }
#pragma unroll
    for (int n = 0; n < 4; ++n) {
        float gg = ngm[n * 16 + c16], bb = nbe[n * 16 + c16];
#pragma unroll
        for (int r = 0; r < 4; ++r) {
            int rowi = g * 4 + r;
            int node = nbase + rowi;
            float v = (acc[n][r] - mu[r]) * rs[r] * gg + bb;
            if (node < N) {
                size_t o = (size_t)node * 64 + n * 16 + c16;
                xout[o] = x[o] + v;
            }
        }
    }
}

// ---------- launcher ----------
extern "C" void kernel_launch(void* const* d_in, const int* in_sizes, int n_in,
                              void* d_out, int out_size, void* d_ws, size_t ws_size,
                              hipStream_t stream)
{
    const float* x   = (const float*)d_in[0];
    const int*   ei  = (const int*)d_in[1];
    const float* ea  = (const float*)d_in[2];
    const float* ew0 = (const float*)d_in[3];
    const float* eb0 = (const float*)d_in[4];
    const float* ew1 = (const float*)d_in[5];
    const float* eb1 = (const float*)d_in[6];
    const float* ew2 = (const float*)d_in[7];
    const float* eb2 = (const float*)d_in[8];
    const float* egm = (const float*)d_in[9];
    const float* ebe = (const float*)d_in[10];
    const float* nw0 = (const float*)d_in[11];
    const float* nb0 = (const float*)d_in[12];
    const float* nw1 = (const float*)d_in[13];
    const float* nb1 = (const float*)d_in[14];
    const float* nw2 = (const float*)d_in[15];
    const float* nb2 = (const float*)d_in[16];
    const float* ngm = (const float*)d_in[17];
    const float* nbe = (const float*)d_in[18];
    const float* wq  = (const float*)d_in[19];
    const float* wk  = (const float*)d_in[20];
    const float* wv  = (const float*)d_in[21];
    const float* wo  = (const float*)d_in[22];

    const int Nn = in_sizes[0] / 64;
    const int Ee = in_sizes[1] / 2;

    char* p = (char*)d_ws;
    auto carve = [&](size_t bytes) {
        char* r = p;
        p += (bytes + 255) & ~(size_t)255;
        return r;
    };
    bf16* W0e = (bf16*)carve(64 * 192 * 2);
    bf16* W1e = (bf16*)carve(64 * 64 * 2);
    bf16* W2e = (bf16*)carve(64 * 64 * 2);
    bf16* Wqb = (bf16*)carve(64 * 64 * 2);
    bf16* Wkb = (bf16*)carve(64 * 64 * 2);
    bf16* Wvb = (bf16*)carve(64 * 64 * 2);
    bf16* Wob = (bf16*)carve(64 * 64 * 2);
    bf16* W0n = (bf16*)carve(64 * 128 * 2);
    bf16* W1n = (bf16*)carve(64 * 64 * 2);
    bf16* W2n = (bf16*)carve(64 * 64 * 2);
    float* scores = (float*)carve((size_t)Ee * 4 * 4);
    bf16*  V      = (bf16*)carve((size_t)Ee * 64 * 2);
    bf16*  msg    = (bf16*)carve((size_t)Nn * 64 * 2);
    int*   deg    = (int*)carve((size_t)Nn * 4);
    int*   ofs    = (int*)carve((size_t)Nn * 4);
    int*   cur    = (int*)carve((size_t)Nn * 4);
    int*   eidT   = (int*)carve((size_t)Ee * 4);
    int*   bsum   = (int*)carve(((size_t)Nn / 256 + 2) * 4);

    hipMemsetAsync(deg, 0, (size_t)Nn * 4, stream);
    hipMemsetAsync(cur, 0, (size_t)Nn * 4, stream);

    PrepArgs pa;
    const float* srcs[10] = {ew0, ew1, ew2, wq, wk, wv, wo, nw0, nw1, nw2};
    bf16* dsts[10]        = {W0e, W1e, W2e, Wqb, Wkb, Wvb, Wob, W0n, W1n, W2n};
    const int sizes[10]   = {12288, 4096, 4096, 4096, 4096, 4096, 4096, 8192, 4096, 4096};
    const int ldks[10]    = {192, 64, 64, 64, 64, 64, 64, 128, 64, 64};
    int acc_ofs = 0;
    for (int i = 0; i < 10; ++i) {
        pa.src[i] = srcs[i];
        pa.dst[i] = dsts[i];
        pa.ofs[i] = acc_ofs;
        pa.ldk[i] = ldks[i];
        acc_ofs += sizes[i];
    }
    pa.ofs[10] = acc_ofs;
    const int totalFrag = acc_ofs / 8;
    prep_kernel<<<(totalFrag + 255) / 256, 256, 0, stream>>>(pa, totalFrag);

    float* xout = (float*)d_out;
    float* eout = (float*)d_out + (size_t)Nn * 64;

    // edge MLP + scores + V + degree histogram
    e1_kernel<<<Ee / 128, 256, 0, stream>>>(x, ei, ea, W0e, W1e, W2e, Wqb, Wkb, Wvb,
                                            eb0, eb1, eb2, egm, ebe,
                                            scores, deg, V, eout, Ee);

    // CSR offsets (exclusive scan of deg)
    const int nb = (Nn + 255) / 256;
    scan1_kernel<<<nb, 256, 0, stream>>>(deg, ofs, bsum, Nn);
    scan2_kernel<<<1, 256, 0, stream>>>(bsum, nb);
    scan3_kernel<<<nb, 256, 0, stream>>>(ofs, bsum, Nn);
    fill_kernel<<<(Ee + 255) / 256, 256, 0, stream>>>(ei, ofs, cur, eidT, Ee);

    // per-node softmax-weighted gather
    gather_kernel<<<(Nn + 3) / 4, 256, 0, stream>>>(deg, ofs, eidT, scores, V, msg, Nn);

    // node MLP
    n_kernel<<<(Nn + 63) / 64, 256, 0, stream>>>(x, msg, Wob, W0n, W1n, W2n,
                                                 nb0, nb1, nb2, ngm, nbe, xout, Nn);
}